// Round 5
// baseline (287.433 us; speedup 1.0000x reference)
//
#include <hip/hip_runtime.h>
#include <hip/hip_bf16.h>
#include <math.h>

#define NB 16
#define SS 64
#define HH 256
#define FAA 256

using short8 = __attribute__((ext_vector_type(8))) short;
using f32x4  = __attribute__((ext_vector_type(4))) float;

__device__ __forceinline__ unsigned short f2bf(float f) {
  union { float f; unsigned int u; } x; x.f = f;
  unsigned int u = x.u;
  return (unsigned short)((u + 0x7FFFu + ((u >> 16) & 1u)) >> 16);  // RNE
}
__device__ __forceinline__ unsigned int cvtpk(float a, float b) {
  unsigned int r;
  asm("v_cvt_pk_bf16_f32 %0, %1, %2" : "=v"(r) : "v"(a), "v"(b));  // RNE, a->lo b->hi
  return r;
}
// select a[q] without runtime vector indexing (dyn-indexed regs -> scratch)
__device__ __forceinline__ float sel4(const f32x4 a, int q) {
  const float s01 = (q & 1) ? a[1] : a[0];
  const float s23 = (q & 1) ? a[3] : a[2];
  return (q & 2) ? s23 : s01;
}

// ---------------------------------------------------------------------------
// Fused prolog: (blocks 0..4351) fp32->bf16 conversions; (blocks 4352..4607)
// fact_proj. The two are independent -> one launch removes a serialization
// point in the 5-deep kernel chain.
// wcat layout: rows 0..255 = Ur[o][k], rows 256..511 = U[o-256][k], with the
// K dimension PERMUTED so actual cols (g*32+l, g*32+16+l) sit at storage
// (g*32+2l, g*32+2l+1). gru_scan stores C in the same permuted order; nmbf's
// middle K-section carries the identical permutation so phase D is invariant.
// ---------------------------------------------------------------------------
__global__ __launch_bounds__(256) void prolog_fused(
    const float* __restrict__ z1w, const float* __restrict__ Ur,
    const float* __restrict__ U, const float* __restrict__ nmw,
    const float* __restrict__ pm, const float* __restrict__ qs,
    unsigned short* __restrict__ z1wbf, unsigned short* __restrict__ wcatbf,
    unsigned short* __restrict__ nmbf, unsigned short* __restrict__ pmbf,
    unsigned short* __restrict__ qbf,
    const float* __restrict__ facts, const float* __restrict__ Wr,
    const float* __restrict__ Wrb, const float* __restrict__ Urb,
    const float* __restrict__ Ww, const float* __restrict__ Wb,
    float* __restrict__ FWr, float* __restrict__ FW) {
  __shared__ float fl[4][HH];
  if (blockIdx.x >= 4352) {
    // ---- fact_proj: FWr[b,h] = facts[b]·Wr[h]+Wr_b[h]+Ur_b[h]; FW = facts[b]·W[h]+W_b[h]
    const int b0 = (blockIdx.x - 4352) * 4;
    const int tid = threadIdx.x;
#pragma unroll
    for (int r = 0; r < 4; ++r) fl[r][tid] = facts[(b0 + r) * HH + tid];
    __syncthreads();
    float ar[4] = {0.f, 0.f, 0.f, 0.f}, aw[4] = {0.f, 0.f, 0.f, 0.f};
    const float4* wr = (const float4*)(Wr + tid * HH);
    const float4* ww = (const float4*)(Ww + tid * HH);
    for (int d4 = 0; d4 < 64; ++d4) {
      float4 a = wr[d4], b = ww[d4];
#pragma unroll
      for (int r = 0; r < 4; ++r) {
        float4 f = *(const float4*)&fl[r][d4 * 4];  // LDS broadcast
        ar[r] += a.x * f.x + a.y * f.y + a.z * f.z + a.w * f.w;
        aw[r] += b.x * f.x + b.y * f.y + b.z * f.z + b.w * f.w;
      }
    }
    const float br = Wrb[tid] + Urb[tid], bw = Wb[tid];
#pragma unroll
    for (int r = 0; r < 4; ++r) {
      FWr[(b0 + r) * HH + tid] = ar[r] + br;
      FW[(b0 + r) * HH + tid] = aw[r] + bw;
    }
    return;
  }
  // ---- conversions
  int idx = blockIdx.x * 256 + threadIdx.x;
  if (idx < 262144) { z1wbf[idx] = f2bf(z1w[idx]); return; }
  idx -= 262144;
  if (idx < 131072) {
    int o = idx >> 8, s = idx & 255;
    int t = s & 31;
    int cc = (s & ~31) + (t >> 1) + ((t & 1) << 4);  // storage s -> actual col
    wcatbf[idx] = f2bf(o < 256 ? Ur[o * 256 + cc] : U[(o - 256) * 256 + cc]);
    return;
  }
  idx -= 131072;
  if (idx < 196608) {
    int o = idx / 768, k = idx - o * 768;
    int kk = k;
    if (k >= 256 && k < 512) {
      int s = k - 256, t = s & 31;
      kk = 256 + (s & ~31) + (t >> 1) + ((t & 1) << 4);
    }
    nmbf[idx] = f2bf(nmw[o * 768 + kk]);
    return;
  }
  idx -= 196608;
  if (idx < 262144) { pmbf[idx] = f2bf(pm[idx]); return; }
  idx -= 262144;
  if (idx < 262144) { qbf[idx] = f2bf(qs[idx]); return; }
}

// ---------------------------------------------------------------------------
// Phase A: gate GEMM + FUSED masked softmax. Block = (n, 2 i's) = 128 rows,
// 256 cols, K=1024 processed as 32 chunks of 32 (hc outer, section s inner;
// accumulation order bit-identical across rounds).
//  - B chunk staged via global_load_lds width=16; A chunk built by VALU from
//    register-prefetched f/q/m; both double-buffered, one barrier per chunk
//  - 16B-slot XOR swizzle on LDS writes+reads -> 2-way max conflicts
//  - launch_bounds(512,4) -> 2 blocks/CU: cross-block overlap fills barrier gaps
// ---------------------------------------------------------------------------
__global__ __launch_bounds__(512, 4) void gate_gemm(
    const float* __restrict__ facts, const float* __restrict__ prevM,
    const float* __restrict__ questions, const unsigned short* __restrict__ z1wbf,
    const float* __restrict__ z1b, const float* __restrict__ z2w,
    const float* __restrict__ z2b, const int* __restrict__ doc_len,
    float* __restrict__ attn) {
  __shared__ unsigned short Ab[2][128 * 32];  // 8KB per buf
  __shared__ unsigned short Bb[2][256 * 32];  // 16KB per buf
  __shared__ float Gpart[128][4];

  const int bi = blockIdx.x;
  const int n = bi >> 5, i0 = (bi & 31) * 2;
  const int tid = threadIdx.x;
  const int w = tid >> 6, l = tid & 63;
  const int rg = w >> 2, cg = w & 3;        // rowgroup (2), colgroup (4)
  const int l15 = l & 15, q = l >> 4;
  const int t15 = tid & 15, jb = tid >> 4;  // builder mapping (jb 0..31)

  const float* fn = facts + n * SS * HH;
  const float* qn = questions + (n * SS + i0) * HH;
  const float* mn = prevM + (n * SS + i0) * HH;

  auto stageB = [&](int buf, int hc, int s) {
    const int kb = s * 256 + hc * 32;
    const int swz = ((l & 3) ^ ((l >> 2) & 3)) * 8;  // colg&3 == (l>>2)&3
#pragma unroll
    for (int j = 0; j < 2; ++j) {
      const int colg = w * 32 + j * 16 + (l >> 2);
      const unsigned short* src = z1wbf + colg * 1024 + kb + swz;
      __builtin_amdgcn_global_load_lds(src, Bb[buf] + (w * 32 + j * 16) * 32, 16, 0, 0);
    }
  };

  auto buildA = [&](int buf, int s, float2 f0, float2 f1, float2 q0, float2 q1,
                    float2 m0, float2 m1) {
    unsigned int* dst = (unsigned int*)Ab[buf];
    const int dsw = t15 ^ ((jb & 3) << 2);  // swizzled 4B-slot (row&3 == jb&3)
    const float2 o0 = (s & 1) ? m0 : q0;
    const float2 o1 = (s & 1) ? m1 : q1;
#pragma unroll
    for (int pl = 0; pl < 2; ++pl) {
      const float fx = pl ? f1.x : f0.x;
      const float fy = pl ? f1.y : f0.y;
#pragma unroll
      for (int il = 0; il < 2; ++il) {
        const int row = il * 64 + pl * 32 + jb;
        const float ox = il ? o1.x : o0.x;
        const float oy = il ? o1.y : o0.y;
        float a, b;
        if (s < 2) { a = fx * ox;         b = fy * oy; }
        else       { a = fabsf(fx - ox);  b = fabsf(fy - oy); }
        dst[row * 16 + dsw] = cvtpk(a, b);
      }
    }
  };

  const f32x4 zero4 = {0.f, 0.f, 0.f, 0.f};
  f32x4 acc[4][4];
#pragma unroll
  for (int a = 0; a < 4; ++a)
#pragma unroll
    for (int b = 0; b < 4; ++b) acc[a][b] = zero4;

  auto mfmaStep = [&](int buf) {
    short8 Bfr[4];
#pragma unroll
    for (int nf = 0; nf < 4; ++nf) {
      const int col = cg * 64 + nf * 16 + l15;
      Bfr[nf] = *(const short8*)&Bb[buf][col * 32 + (q ^ (l15 & 3)) * 8];
    }
    __builtin_amdgcn_s_setprio(1);
#pragma unroll
    for (int mf = 0; mf < 4; ++mf) {
      const int row = rg * 64 + mf * 16 + l15;
      const short8 Afm = *(const short8*)&Ab[buf][row * 32 + (q ^ (l15 & 3)) * 8];
#pragma unroll
      for (int nf = 0; nf < 4; ++nf)
        acc[mf][nf] = __builtin_amdgcn_mfma_f32_16x16x32_bf16(Afm, Bfr[nf], acc[mf][nf], 0, 0, 0);
    }
    __builtin_amdgcn_s_setprio(0);
  };

  const int hh2 = t15 * 2;
  auto pf = [&](int hc, float2& f0, float2& f1, float2& q0, float2& q1,
                float2& m0, float2& m1) {
    const int h = hc * 32 + hh2;
    f0 = *(const float2*)(fn + jb * HH + h);
    f1 = *(const float2*)(fn + (jb + 32) * HH + h);
    q0 = *(const float2*)(qn + h);
    q1 = *(const float2*)(qn + HH + h);
    m0 = *(const float2*)(mn + h);
    m1 = *(const float2*)(mn + HH + h);
  };

  float2 Rf0, Rf1, Rq0, Rq1, Rm0, Rm1;    // current hc operands
  float2 Sf0, Sf1, Sq0, Sq1, Sm0, Sm1;    // next hc operands
  pf(0, Rf0, Rf1, Rq0, Rq1, Rm0, Rm1);
  stageB(0, 0, 0);
  buildA(0, 0, Rf0, Rf1, Rq0, Rq1, Rm0, Rm1);
  __syncthreads();

  int buf = 0;
  for (int hc = 0; hc < 8; ++hc) {
    stageB(buf ^ 1, hc, 1);
    buildA(buf ^ 1, 1, Rf0, Rf1, Rq0, Rq1, Rm0, Rm1);
    mfmaStep(buf);
    __syncthreads();
    buf ^= 1;
    stageB(buf ^ 1, hc, 2);
    buildA(buf ^ 1, 2, Rf0, Rf1, Rq0, Rq1, Rm0, Rm1);
    mfmaStep(buf);
    __syncthreads();
    buf ^= 1;
    stageB(buf ^ 1, hc, 3);
    buildA(buf ^ 1, 3, Rf0, Rf1, Rq0, Rq1, Rm0, Rm1);
    if (hc < 7) pf(hc + 1, Sf0, Sf1, Sq0, Sq1, Sm0, Sm1);
    mfmaStep(buf);
    __syncthreads();
    buf ^= 1;
    if (hc < 7) {
      stageB(buf ^ 1, hc + 1, 0);
      buildA(buf ^ 1, 0, Sf0, Sf1, Sq0, Sq1, Sm0, Sm1);
    }
    mfmaStep(buf);
    __syncthreads();
    buf ^= 1;
    Rf0 = Sf0; Rf1 = Sf1; Rq0 = Sq0; Rq1 = Sq1; Rm0 = Sm0; Rm1 = Sm1;
  }

  // epilogue: tanh, scale by z2_w, reduce over k
  float psum[4][4];
#pragma unroll
  for (int mf = 0; mf < 4; ++mf)
#pragma unroll
    for (int v = 0; v < 4; ++v) psum[mf][v] = 0.f;

#pragma unroll
  for (int nf = 0; nf < 4; ++nf) {
    const int k = cg * 64 + nf * 16 + l15;
    const float zb = z1b[k], zw = z2w[k];
#pragma unroll
    for (int mf = 0; mf < 4; ++mf)
#pragma unroll
      for (int v = 0; v < 4; ++v) {
        const float x = acc[mf][nf][v] + zb;
        const float e = __expf(2.f * x);
        const float t = 1.f - 2.f / (e + 1.f);  // tanh(x)
        psum[mf][v] += zw * t;
      }
  }
#pragma unroll
  for (int d = 1; d < 16; d <<= 1)
#pragma unroll
    for (int mf = 0; mf < 4; ++mf)
#pragma unroll
      for (int v = 0; v < 4; ++v) psum[mf][v] += __shfl_xor(psum[mf][v], d, 64);
  if (l15 == 0) {
#pragma unroll
    for (int mf = 0; mf < 4; ++mf)
#pragma unroll
      for (int v = 0; v < 4; ++v)
        Gpart[rg * 64 + mf * 16 + q * 4 + v][cg] = psum[mf][v];
  }
  __syncthreads();
  if (tid < 128) {  // waves 0,1 fully active: wave = row i, lane = j
    const float gg = Gpart[tid][0] + Gpart[tid][1] + Gpart[tid][2] + Gpart[tid][3] + z2b[0];
    const int i = i0 + (tid >> 6), j = tid & 63;
    const int dl = doc_len[n];
    const float x = (j < dl && gg != 0.0f) ? gg : -INFINITY;  // where(G*mask==0,-inf)
    float mx = x;
#pragma unroll
    for (int d = 1; d < 64; d <<= 1) mx = fmaxf(mx, __shfl_xor(mx, d, 64));
    const float e = (x == -INFINITY) ? 0.f : __expf(x - mx);
    float s = e;
#pragma unroll
    for (int d = 1; d < 64; d <<= 1) s += __shfl_xor(s, d, 64);
    attn[(n * SS + i) * SS + j] = e / s;
  }
}

// ---------------------------------------------------------------------------
// Phase C: GRU-style scan. Block = (n, 4 rows), 256 blocks = all 256 CUs.
// Rows dup'd 4x in M=16 (broadcast A-read); lane (q,l15) updates row q only.
// THIS ROUND (was 74us, MfmaUtil 36.7 ~= VALUBusy 36.6 -> serialized phases +
// per-step vmcnt(0) barrier drain exposing FWr/FW HBM-miss latency):
//  1. raw "lgkmcnt(0); s_barrier" (no vmcnt drain: global loads are private)
//  2. FWr/FW prefetch 2 steps deep -> 900cy HBM miss resolves across 2 steps
//  3. MFMA chains f0,f2 -> f1,f3 -> cell-0 VALU (overlaps f1/f3 pipe drain)
//  4. LDS pad >80KB forces 1 block/CU (insurance against dispatcher packing)
// ---------------------------------------------------------------------------
__global__ __launch_bounds__(512, 2) void gru_scan(
    const unsigned short* __restrict__ wcat, const float* __restrict__ FWr,
    const float* __restrict__ FW, const float* __restrict__ Ub,
    const float* __restrict__ attn, unsigned short* __restrict__ Cout) {
  __shared__ unsigned short Cbf[2][4 * 272];  // stride 272 sh (136 dw, 8 mod 32 -> 2-way)
  __shared__ float attn_sT[64 * 4];           // [t][row]
  __shared__ float lds_pad[20608];            // 80.5KB pad -> exactly 1 block/CU

  const int bi = blockIdx.x, n = bi >> 4, i0 = (bi & 15) * 4;
  const int tid = threadIdx.x, w = tid >> 6, l = tid & 63;
  const int l15 = l & 15, q = l >> 4;
  const int h0 = w * 32 + l15;  // lane's actual h cols: h0 and h0+16

  if (tid == 0) lds_pad[0] = 0.f;  // keep pad allocated

  // persistent B-fragments: f=0/1 -> Ur cols h0/h0+16 ; f=2/3 -> U cols (K perm'd)
  short8 Bf[8][4];
#pragma unroll
  for (int f = 0; f < 4; ++f) {
    const int wrow = ((f >> 1) ? 256 : 0) + w * 32 + (f & 1) * 16 + l15;
    const unsigned short* bb = wcat + wrow * 256 + q * 8;
#pragma unroll
    for (int kt = 0; kt < 8; ++kt)
      Bf[kt][f] = *(const short8*)(bb + kt * 32);
  }

  const float ub0 = Ub[h0], ub1 = Ub[h0 + 16];

  for (int e = tid; e < 64 * 4; e += 512)  // attn transposed: [t][row]
    attn_sT[e] = attn[(n * SS + i0 + (e & 3)) * SS + (e >> 2)];
  for (int e = tid; e < 544; e += 512)
    ((unsigned int*)Cbf[0])[e] = 0u;
  __syncthreads();

  const float* fwr_g = FWr + n * SS * HH;
  const float* fw_g  = FW + n * SS * HH;

  float cm0 = 0.f, cm1 = 0.f;  // fp32 master state: (row q, h0) and (row q, h0+16)
  // 2-deep FWr/FW pipeline: A = step t, B = step t+1
  float frA0 = fwr_g[h0], frA1 = fwr_g[h0 + 16];
  float fcA0 = fw_g[h0],  fcA1 = fw_g[h0 + 16];
  float frB0 = fwr_g[HH + h0], frB1 = fwr_g[HH + h0 + 16];
  float fcB0 = fw_g[HH + h0],  fcB1 = fw_g[HH + h0 + 16];

  for (int t = 0; t < 64; ++t) {
    const int cur = t & 1;
    const unsigned short* Cr = Cbf[cur];
    unsigned int* Cw = (unsigned int*)Cbf[cur ^ 1];

    // A-fragments: row (l15&3) -> 4-way broadcast read
    short8 Af[8];
    const int arow = (l15 & 3) * 272;
#pragma unroll
    for (int kt = 0; kt < 8; ++kt)
      Af[kt] = *(const short8*)&Cr[arow + kt * 32 + q * 8];

    // issue loads for step t+2 (consumed 2 barriers later; never drained early)
    float nr0 = 0.f, nr1 = 0.f, nc0 = 0.f, nc1 = 0.f;
    if (t < 62) {
      const float* a = fwr_g + (t + 2) * HH;
      const float* b = fw_g + (t + 2) * HH;
      nr0 = a[h0]; nr1 = a[h0 + 16];
      nc0 = b[h0]; nc1 = b[h0 + 16];
    }

    const f32x4 z4 = {0.f, 0.f, 0.f, 0.f};
    f32x4 a0 = z4, a1 = z4, a2 = z4, a3 = z4;
    __builtin_amdgcn_s_setprio(1);
#pragma unroll
    for (int kt = 0; kt < 8; ++kt) {
      a0 = __builtin_amdgcn_mfma_f32_16x16x32_bf16(Af[kt], Bf[kt][0], a0, 0, 0, 0);
      a2 = __builtin_amdgcn_mfma_f32_16x16x32_bf16(Af[kt], Bf[kt][2], a2, 0, 0, 0);
    }
#pragma unroll
    for (int kt = 0; kt < 8; ++kt) {
      a1 = __builtin_amdgcn_mfma_f32_16x16x32_bf16(Af[kt], Bf[kt][1], a1, 0, 0, 0);
      a3 = __builtin_amdgcn_mfma_f32_16x16x32_bf16(Af[kt], Bf[kt][3], a3, 0, 0, 0);
    }
    __builtin_amdgcn_s_setprio(0);

    const float g = attn_sT[t * 4 + q];  // 16-lane broadcast

    // cell 0 (needs a0,a2 only -> VALU overlaps a1/a3 MFMA pipe drain)
    const float yr0 = sel4(a0, q), yu0 = sel4(a2, q);
    const float r0 = 1.f / (1.f + __expf(-(frA0 + yr0)));
    const float x0 = fcA0 + r0 * (yu0 + ub0);
    const float e0 = __expf(2.f * x0);
    const float h0t = 1.f - 2.f / (e0 + 1.f);
    cm0 += g * (h0t - cm0);

    // cell 1
    const float yr1 = sel4(a1, q), yu1 = sel4(a3, q);
    const float r1 = 1.f / (1.f + __expf(-(frA1 + yr1)));
    const float x1 = fcA1 + r1 * (yu1 + ub1);
    const float e1 = __expf(2.f * x1);
    const float h1t = 1.f - 2.f / (e1 + 1.f);
    cm1 += g * (h1t - cm1);

    Cw[q * 136 + w * 16 + l15] = cvtpk(cm0, cm1);  // storage cols (2*l15, 2*l15+1)

    frA0 = frB0; frA1 = frB1; fcA0 = fcB0; fcA1 = fcB1;
    frB0 = nr0; frB1 = nr1; fcB0 = nc0; fcB1 = nc1;

    // raw barrier: LDS visibility only (no vmcnt(0) drain of the prefetch)
    asm volatile("s_waitcnt lgkmcnt(0)\n\ts_barrier" ::: "memory");
  }

  // final state in Cbf[0] (t=63 wrote buf 0); 4 rows x 128 dwords
  {
    const int row = tid >> 7, wo = tid & 127;
    ((unsigned int*)Cout)[(n * SS + i0 + row) * 128 + wo] =
        *(const unsigned int*)&Cbf[0][row * 272 + wo * 2];
  }
}

// ---------------------------------------------------------------------------
// Phase D: next_mem = relu([prevM | C | questions] @ nm_w^T + nm_b)
// Tile 64 rows x 32 cols -> 128 blocks.
// (cbf and nmbf's middle K-section share the same K permutation -> invariant)
// ---------------------------------------------------------------------------
__global__ __launch_bounds__(256) void next_mem_gemm(
    const unsigned short* __restrict__ pmbf, const unsigned short* __restrict__ cbf,
    const unsigned short* __restrict__ qbf, const unsigned short* __restrict__ nmbf,
    const float* __restrict__ nmb, float* __restrict__ out) {
  __shared__ unsigned short A[64][40];  // stride 40 bf16 (20 words -> 2-way max)
  const int bi = blockIdx.x;
  const int rb = bi >> 3, cb = bi & 7;
  const int r0 = rb * 64, c0 = cb * 32;
  const int tid = threadIdx.x, w = tid >> 6, l = tid & 63;
  const int l15 = l & 15, q = l >> 4;

  f32x4 acc[2];
  const f32x4 z4 = {0.f, 0.f, 0.f, 0.f};
#pragma unroll
  for (int nf = 0; nf < 2; ++nf) acc[nf] = z4;

  for (int kt = 0; kt < 24; ++kt) {
    const int kg = kt * 32;
    const unsigned short* src =
        kg < 256 ? (pmbf + kg) : (kg < 512 ? (cbf + kg - 256) : (qbf + kg - 512));
    const int kk = (tid & 15) * 2;
#pragma unroll
    for (int ps = 0; ps < 4; ++ps) {
      const int row = ps * 16 + (tid >> 4);
      *(unsigned int*)&A[row][kk] = *(const unsigned int*)(src + (r0 + row) * HH + kk);
    }
    __syncthreads();
    short8 Bfr[2];
#pragma unroll
    for (int nf = 0; nf < 2; ++nf)
      Bfr[nf] = *(const short8*)(nmbf + (c0 + nf * 16 + l15) * 768 + kg + q * 8);
    const short8 Af = *(const short8*)&A[w * 16 + l15][q * 8];
#pragma unroll
    for (int nf = 0; nf < 2; ++nf)
      acc[nf] = __builtin_amdgcn_mfma_f32_16x16x32_bf16(Af, Bfr[nf], acc[nf], 0, 0, 0);
    __syncthreads();
  }
#pragma unroll
  for (int nf = 0; nf < 2; ++nf) {
    const int col = c0 + nf * 16 + l15;
    const float bv = nmb[col];
#pragma unroll
    for (int v = 0; v < 4; ++v) {
      const int grow = r0 + w * 16 + q * 4 + v;
      out[grow * HH + col] = fmaxf(acc[nf][v] + bv, 0.f);
    }
  }
}

// ---------------------------------------------------------------------------
extern "C" void kernel_launch(void* const* d_in, const int* in_sizes, int n_in,
                              void* d_out, int out_size, void* d_ws, size_t ws_size,
                              hipStream_t stream) {
  const float* facts     = (const float*)d_in[0];
  const float* prevM     = (const float*)d_in[1];
  const float* questions = (const float*)d_in[2];
  const int*   doc_len   = (const int*)d_in[3];
  const float* z1w = (const float*)d_in[4];
  const float* z1b = (const float*)d_in[5];
  const float* z2w = (const float*)d_in[6];
  const float* z2b = (const float*)d_in[7];
  const float* Wrw = (const float*)d_in[8];
  const float* Wrb = (const float*)d_in[9];
  const float* Urw = (const float*)d_in[10];
  const float* Urb = (const float*)d_in[11];
  const float* Ww  = (const float*)d_in[12];
  const float* Wb  = (const float*)d_in[13];
  const float* Uw  = (const float*)d_in[14];
  const float* Ub  = (const float*)d_in[15];
  const float* nmw = (const float*)d_in[16];
  const float* nmb = (const float*)d_in[17];

  char* ws = (char*)d_ws;
  unsigned short* z1wbf  = (unsigned short*)(ws + 0);        // 512 KB
  unsigned short* wcatbf = (unsigned short*)(ws + 524288);   // 256 KB
  unsigned short* nmbf   = (unsigned short*)(ws + 786432);   // 384 KB
  unsigned short* pmbf   = (unsigned short*)(ws + 1179648);  // 512 KB
  unsigned short* qbf    = (unsigned short*)(ws + 1703936);  // 512 KB
  float* FWr = (float*)(ws + 2490368);                       // 1 MB
  float* FW  = (float*)(ws + 3538944);                       // 1 MB
  unsigned short* cbf = (unsigned short*)(ws + 4587520);     // 512 KB  (total ~4.9 MB)

  float* out  = (float*)d_out;
  float* attn = out + NB * SS * HH;  // second output region

  prolog_fused<<<4608, 256, 0, stream>>>(z1w, Urw, Uw, nmw, prevM, questions,
                                         z1wbf, wcatbf, nmbf, pmbf, qbf,
                                         facts, Wrw, Wrb, Urb, Ww, Wb, FWr, FW);
  gate_gemm<<<512, 512, 0, stream>>>(facts, prevM, questions, z1wbf, z1b, z2w, z2b,
                                     doc_len, attn);
  gru_scan<<<256, 512, 0, stream>>>(wcatbf, FWr, FW, Ub, attn, cbf);
  next_mem_gemm<<<128, 256, 0, stream>>>(pmbf, cbf, qbf, nmbf, nmb, out);
}

// Round 6
// 246.331 us; speedup vs baseline: 1.1669x; 1.1669x over previous
//
#include <hip/hip_runtime.h>
#include <hip/hip_bf16.h>
#include <math.h>

#define NB 16
#define SS 64
#define HH 256
#define FAA 256

using short8 = __attribute__((ext_vector_type(8))) short;
using f32x4  = __attribute__((ext_vector_type(4))) float;

__device__ __forceinline__ unsigned int cvtpk(float a, float b) {
  unsigned int r;
  asm("v_cvt_pk_bf16_f32 %0, %1, %2" : "=v"(r) : "v"(a), "v"(b));  // RNE, a->lo b->hi
  return r;
}
// select a[q] without runtime vector indexing (dyn-indexed regs -> scratch)
__device__ __forceinline__ float sel4(const f32x4 a, int q) {
  const float s01 = (q & 1) ? a[1] : a[0];
  const float s23 = (q & 1) ? a[3] : a[2];
  return (q & 2) ? s23 : s01;
}

// ---------------------------------------------------------------------------
// Fused prolog, VECTORIZED (was 4608 blocks x 1 scalar elem/thread -> dispatch/
// granularity-bound at 90-104us with all pipes <6%; roofline ~1.5us).
// Now 8 elems/thread: 2x float4 loads + 4x cvt_pk + one 16B store.
// Block map: [0,128) z1w | [128,192) wcat | [192,288) nmbf | [288,416) pm |
//            [416,544) q | [544,800) fact_proj.
// wcat/nmbf K-PERMUTATION (storage (g*32+2l, g*32+2l+1) = actual cols
// (g*32+l, g*32+16+l)) vectorizes as two contiguous float4 gathers per thread
// (cols c..c+3 and c+16..c+19). gru_scan stores C in the same permuted order;
// nmbf's middle K-section carries the identical permutation -> phase D invariant.
// ---------------------------------------------------------------------------
__global__ __launch_bounds__(256) void prolog_fused(
    const float* __restrict__ z1w, const float* __restrict__ Ur,
    const float* __restrict__ U, const float* __restrict__ nmw,
    const float* __restrict__ pm, const float* __restrict__ qs,
    unsigned short* __restrict__ z1wbf, unsigned short* __restrict__ wcatbf,
    unsigned short* __restrict__ nmbf, unsigned short* __restrict__ pmbf,
    unsigned short* __restrict__ qbf,
    const float* __restrict__ facts, const float* __restrict__ Wr,
    const float* __restrict__ Wrb, const float* __restrict__ Urb,
    const float* __restrict__ Ww, const float* __restrict__ Wb,
    float* __restrict__ FWr, float* __restrict__ FW) {
  __shared__ float fl[4][HH];
  const int bid = blockIdx.x, tid = threadIdx.x;

  auto cvt8 = [&](const float* src, unsigned short* dst, int base) {
    const float4 a = *(const float4*)(src + base);
    const float4 b = *(const float4*)(src + base + 4);
    uint4 o;
    o.x = cvtpk(a.x, a.y); o.y = cvtpk(a.z, a.w);
    o.z = cvtpk(b.x, b.y); o.w = cvtpk(b.z, b.w);
    *(uint4*)(dst + base) = o;  // base mult of 8 -> 16B aligned
  };
  // permuted pair-pack: storage u32 w holds (row[c0+w], row[c0+16+w])
  auto cvt8perm = [&](const float* row, unsigned short* dst, int sbase, int c0) {
    const float4 lo = *(const float4*)(row + c0);
    const float4 hi = *(const float4*)(row + c0 + 16);
    uint4 o;
    o.x = cvtpk(lo.x, hi.x); o.y = cvtpk(lo.y, hi.y);
    o.z = cvtpk(lo.z, hi.z); o.w = cvtpk(lo.w, hi.w);
    *(uint4*)(dst + sbase) = o;
  };

  if (bid < 128) {               // z1w: 262144 elems
    const int base = (bid * 256 + tid) * 8;
    cvt8(z1w, z1wbf, base);
    return;
  }
  if (bid < 192) {               // wcat: 131072 elems, K-permuted
    const int base = ((bid - 128) * 256 + tid) * 8;
    const int o = base >> 8, s0 = base & 255;
    const int gb = s0 & ~31, t0 = s0 & 31;          // t0 in {0,8,16,24}
    const float* row = (o < 256) ? (Ur + o * 256) : (U + (o - 256) * 256);
    cvt8perm(row, wcatbf, base, gb + (t0 >> 1));
    return;
  }
  if (bid < 288) {               // nmbf: 196608 elems, middle section permuted
    const int base = ((bid - 192) * 256 + tid) * 8;
    const int o = base / 768, k0 = base - o * 768;
    const float* row = nmw + o * 768;
    if (k0 >= 256 && k0 < 512) {
      const int s0 = k0 - 256, gb = s0 & ~31, t0 = s0 & 31;
      cvt8perm(row, nmbf, base, 256 + gb + (t0 >> 1));
    } else {
      cvt8(row, nmbf + o * 768, k0);
    }
    return;
  }
  if (bid < 416) {               // prevM: 262144 elems
    const int base = ((bid - 288) * 256 + tid) * 8;
    cvt8(pm, pmbf, base);
    return;
  }
  if (bid < 544) {               // questions: 262144 elems
    const int base = ((bid - 416) * 256 + tid) * 8;
    cvt8(qs, qbf, base);
    return;
  }
  // ---- fact_proj: FWr[b,h] = facts[b]·Wr[h]+Wr_b[h]+Ur_b[h]; FW = facts[b]·W[h]+W_b[h]
  const int b0 = (bid - 544) * 4;
#pragma unroll
  for (int r = 0; r < 4; ++r) fl[r][tid] = facts[(b0 + r) * HH + tid];
  __syncthreads();
  float ar[4] = {0.f, 0.f, 0.f, 0.f}, aw[4] = {0.f, 0.f, 0.f, 0.f};
  const float4* wr = (const float4*)(Wr + tid * HH);
  const float4* ww = (const float4*)(Ww + tid * HH);
  for (int d4 = 0; d4 < 64; ++d4) {
    float4 a = wr[d4], b = ww[d4];
#pragma unroll
    for (int r = 0; r < 4; ++r) {
      float4 f = *(const float4*)&fl[r][d4 * 4];  // LDS broadcast
      ar[r] += a.x * f.x + a.y * f.y + a.z * f.z + a.w * f.w;
      aw[r] += b.x * f.x + b.y * f.y + b.z * f.z + b.w * f.w;
    }
  }
  const float br = Wrb[tid] + Urb[tid], bw = Wb[tid];
#pragma unroll
  for (int r = 0; r < 4; ++r) {
    FWr[(b0 + r) * HH + tid] = ar[r] + br;
    FW[(b0 + r) * HH + tid] = aw[r] + bw;
  }
}

// ---------------------------------------------------------------------------
// Phase A: gate GEMM + FUSED masked softmax. Block = (n, 2 i's) = 128 rows,
// 256 cols, K=1024 processed as 32 chunks of 32 (hc outer, section s inner;
// accumulation order bit-identical across rounds).
//  - B chunk staged via global_load_lds width=16; A chunk built by VALU from
//    register-prefetched f/q/m; both double-buffered, one barrier per chunk
//  - 16B-slot XOR swizzle on LDS writes+reads -> 2-way max conflicts
//  - launch_bounds(512,4) -> 2 blocks/CU: cross-block overlap fills barrier gaps
// ---------------------------------------------------------------------------
__global__ __launch_bounds__(512, 4) void gate_gemm(
    const float* __restrict__ facts, const float* __restrict__ prevM,
    const float* __restrict__ questions, const unsigned short* __restrict__ z1wbf,
    const float* __restrict__ z1b, const float* __restrict__ z2w,
    const float* __restrict__ z2b, const int* __restrict__ doc_len,
    float* __restrict__ attn) {
  __shared__ unsigned short Ab[2][128 * 32];  // 8KB per buf
  __shared__ unsigned short Bb[2][256 * 32];  // 16KB per buf
  __shared__ float Gpart[128][4];

  const int bi = blockIdx.x;
  const int n = bi >> 5, i0 = (bi & 31) * 2;
  const int tid = threadIdx.x;
  const int w = tid >> 6, l = tid & 63;
  const int rg = w >> 2, cg = w & 3;        // rowgroup (2), colgroup (4)
  const int l15 = l & 15, q = l >> 4;
  const int t15 = tid & 15, jb = tid >> 4;  // builder mapping (jb 0..31)

  const float* fn = facts + n * SS * HH;
  const float* qn = questions + (n * SS + i0) * HH;
  const float* mn = prevM + (n * SS + i0) * HH;

  auto stageB = [&](int buf, int hc, int s) {
    const int kb = s * 256 + hc * 32;
    const int swz = ((l & 3) ^ ((l >> 2) & 3)) * 8;  // colg&3 == (l>>2)&3
#pragma unroll
    for (int j = 0; j < 2; ++j) {
      const int colg = w * 32 + j * 16 + (l >> 2);
      const unsigned short* src = z1wbf + colg * 1024 + kb + swz;
      __builtin_amdgcn_global_load_lds(src, Bb[buf] + (w * 32 + j * 16) * 32, 16, 0, 0);
    }
  };

  auto buildA = [&](int buf, int s, float2 f0, float2 f1, float2 q0, float2 q1,
                    float2 m0, float2 m1) {
    unsigned int* dst = (unsigned int*)Ab[buf];
    const int dsw = t15 ^ ((jb & 3) << 2);  // swizzled 4B-slot (row&3 == jb&3)
    const float2 o0 = (s & 1) ? m0 : q0;
    const float2 o1 = (s & 1) ? m1 : q1;
#pragma unroll
    for (int pl = 0; pl < 2; ++pl) {
      const float fx = pl ? f1.x : f0.x;
      const float fy = pl ? f1.y : f0.y;
#pragma unroll
      for (int il = 0; il < 2; ++il) {
        const int row = il * 64 + pl * 32 + jb;
        const float ox = il ? o1.x : o0.x;
        const float oy = il ? o1.y : o0.y;
        float a, b;
        if (s < 2) { a = fx * ox;         b = fy * oy; }
        else       { a = fabsf(fx - ox);  b = fabsf(fy - oy); }
        dst[row * 16 + dsw] = cvtpk(a, b);
      }
    }
  };

  const f32x4 zero4 = {0.f, 0.f, 0.f, 0.f};
  f32x4 acc[4][4];
#pragma unroll
  for (int a = 0; a < 4; ++a)
#pragma unroll
    for (int b = 0; b < 4; ++b) acc[a][b] = zero4;

  auto mfmaStep = [&](int buf) {
    short8 Bfr[4];
#pragma unroll
    for (int nf = 0; nf < 4; ++nf) {
      const int col = cg * 64 + nf * 16 + l15;
      Bfr[nf] = *(const short8*)&Bb[buf][col * 32 + (q ^ (l15 & 3)) * 8];
    }
    __builtin_amdgcn_s_setprio(1);
#pragma unroll
    for (int mf = 0; mf < 4; ++mf) {
      const int row = rg * 64 + mf * 16 + l15;
      const short8 Afm = *(const short8*)&Ab[buf][row * 32 + (q ^ (l15 & 3)) * 8];
#pragma unroll
      for (int nf = 0; nf < 4; ++nf)
        acc[mf][nf] = __builtin_amdgcn_mfma_f32_16x16x32_bf16(Afm, Bfr[nf], acc[mf][nf], 0, 0, 0);
    }
    __builtin_amdgcn_s_setprio(0);
  };

  const int hh2 = t15 * 2;
  auto pf = [&](int hc, float2& f0, float2& f1, float2& q0, float2& q1,
                float2& m0, float2& m1) {
    const int h = hc * 32 + hh2;
    f0 = *(const float2*)(fn + jb * HH + h);
    f1 = *(const float2*)(fn + (jb + 32) * HH + h);
    q0 = *(const float2*)(qn + h);
    q1 = *(const float2*)(qn + HH + h);
    m0 = *(const float2*)(mn + h);
    m1 = *(const float2*)(mn + HH + h);
  };

  float2 Rf0, Rf1, Rq0, Rq1, Rm0, Rm1;    // current hc operands
  float2 Sf0, Sf1, Sq0, Sq1, Sm0, Sm1;    // next hc operands
  pf(0, Rf0, Rf1, Rq0, Rq1, Rm0, Rm1);
  stageB(0, 0, 0);
  buildA(0, 0, Rf0, Rf1, Rq0, Rq1, Rm0, Rm1);
  __syncthreads();

  int buf = 0;
  for (int hc = 0; hc < 8; ++hc) {
    stageB(buf ^ 1, hc, 1);
    buildA(buf ^ 1, 1, Rf0, Rf1, Rq0, Rq1, Rm0, Rm1);
    mfmaStep(buf);
    __syncthreads();
    buf ^= 1;
    stageB(buf ^ 1, hc, 2);
    buildA(buf ^ 1, 2, Rf0, Rf1, Rq0, Rq1, Rm0, Rm1);
    mfmaStep(buf);
    __syncthreads();
    buf ^= 1;
    stageB(buf ^ 1, hc, 3);
    buildA(buf ^ 1, 3, Rf0, Rf1, Rq0, Rq1, Rm0, Rm1);
    if (hc < 7) pf(hc + 1, Sf0, Sf1, Sq0, Sq1, Sm0, Sm1);
    mfmaStep(buf);
    __syncthreads();
    buf ^= 1;
    if (hc < 7) {
      stageB(buf ^ 1, hc + 1, 0);
      buildA(buf ^ 1, 0, Sf0, Sf1, Sq0, Sq1, Sm0, Sm1);
    }
    mfmaStep(buf);
    __syncthreads();
    buf ^= 1;
    Rf0 = Sf0; Rf1 = Sf1; Rq0 = Sq0; Rq1 = Sq1; Rm0 = Sm0; Rm1 = Sm1;
  }

  // epilogue: tanh, scale by z2_w, reduce over k
  float psum[4][4];
#pragma unroll
  for (int mf = 0; mf < 4; ++mf)
#pragma unroll
    for (int v = 0; v < 4; ++v) psum[mf][v] = 0.f;

#pragma unroll
  for (int nf = 0; nf < 4; ++nf) {
    const int k = cg * 64 + nf * 16 + l15;
    const float zb = z1b[k], zw = z2w[k];
#pragma unroll
    for (int mf = 0; mf < 4; ++mf)
#pragma unroll
      for (int v = 0; v < 4; ++v) {
        const float x = acc[mf][nf][v] + zb;
        const float e = __expf(2.f * x);
        const float t = 1.f - 2.f / (e + 1.f);  // tanh(x)
        psum[mf][v] += zw * t;
      }
  }
#pragma unroll
  for (int d = 1; d < 16; d <<= 1)
#pragma unroll
    for (int mf = 0; mf < 4; ++mf)
#pragma unroll
      for (int v = 0; v < 4; ++v) psum[mf][v] += __shfl_xor(psum[mf][v], d, 64);
  if (l15 == 0) {
#pragma unroll
    for (int mf = 0; mf < 4; ++mf)
#pragma unroll
      for (int v = 0; v < 4; ++v)
        Gpart[rg * 64 + mf * 16 + q * 4 + v][cg] = psum[mf][v];
  }
  __syncthreads();
  if (tid < 128) {  // waves 0,1 fully active: wave = row i, lane = j
    const float gg = Gpart[tid][0] + Gpart[tid][1] + Gpart[tid][2] + Gpart[tid][3] + z2b[0];
    const int i = i0 + (tid >> 6), j = tid & 63;
    const int dl = doc_len[n];
    const float x = (j < dl && gg != 0.0f) ? gg : -INFINITY;  // where(G*mask==0,-inf)
    float mx = x;
#pragma unroll
    for (int d = 1; d < 64; d <<= 1) mx = fmaxf(mx, __shfl_xor(mx, d, 64));
    const float e = (x == -INFINITY) ? 0.f : __expf(x - mx);
    float s = e;
#pragma unroll
    for (int d = 1; d < 64; d <<= 1) s += __shfl_xor(s, d, 64);
    attn[(n * SS + i) * SS + j] = e / s;
  }
}

// ---------------------------------------------------------------------------
// Phase C: GRU-style scan. Block = (n, 4 rows), 256 blocks = all 256 CUs.
// (REVERTED to the round-4 proven version: r5's raw-barrier/2-deep-prefetch/
// LDS-pad changes were neutral-to-negative; the 2-deep prefetch is defeated
// by the register-rotation vmcnt wait anyway.)
// Rows dup'd 4x in M=16 (broadcast A-read); lane (q,l15) updates row q only.
// ---------------------------------------------------------------------------
__global__ __launch_bounds__(512, 2) void gru_scan(
    const unsigned short* __restrict__ wcat, const float* __restrict__ FWr,
    const float* __restrict__ FW, const float* __restrict__ Ub,
    const float* __restrict__ attn, unsigned short* __restrict__ Cout) {
  __shared__ unsigned short Cbf[2][4 * 272];  // stride 272 sh (136 dw, 8 mod 32 -> 2-way)
  __shared__ float attn_sT[64 * 4];           // [t][row]

  const int bi = blockIdx.x, n = bi >> 4, i0 = (bi & 15) * 4;
  const int tid = threadIdx.x, w = tid >> 6, l = tid & 63;
  const int l15 = l & 15, q = l >> 4;
  const int h0 = w * 32 + l15;  // lane's actual h cols: h0 and h0+16

  // persistent B-fragments: f=0/1 -> Ur cols h0/h0+16 ; f=2/3 -> U cols (K perm'd)
  short8 Bf[8][4];
#pragma unroll
  for (int f = 0; f < 4; ++f) {
    const int wrow = ((f >> 1) ? 256 : 0) + w * 32 + (f & 1) * 16 + l15;
    const unsigned short* bb = wcat + wrow * 256 + q * 8;
#pragma unroll
    for (int kt = 0; kt < 8; ++kt)
      Bf[kt][f] = *(const short8*)(bb + kt * 32);
  }

  const float ub0 = Ub[h0], ub1 = Ub[h0 + 16];

  for (int e = tid; e < 64 * 4; e += 512)  // attn transposed: [t][row]
    attn_sT[e] = attn[(n * SS + i0 + (e & 3)) * SS + (e >> 2)];
  for (int e = tid; e < 544; e += 512)
    ((unsigned int*)Cbf[0])[e] = 0u;
  __syncthreads();

  const float* fwr_g = FWr + n * SS * HH;
  const float* fw_g  = FW + n * SS * HH;

  float cm0 = 0.f, cm1 = 0.f;  // fp32 master state: (row q, h0) and (row q, h0+16)
  float fr0 = fwr_g[h0], fr1 = fwr_g[h0 + 16];
  float fc0 = fw_g[h0],  fc1 = fw_g[h0 + 16];

  for (int t = 0; t < 64; ++t) {
    const int cur = t & 1;
    const unsigned short* Cr = Cbf[cur];
    unsigned int* Cw = (unsigned int*)Cbf[cur ^ 1];

    // A-fragments: row (l15&3) -> 4-way broadcast read
    short8 Af[8];
    const int arow = (l15 & 3) * 272;
#pragma unroll
    for (int kt = 0; kt < 8; ++kt)
      Af[kt] = *(const short8*)&Cr[arow + kt * 32 + q * 8];

    // prefetch next step's FWr/FW (consumed next iteration -> latency hidden)
    float nr0 = 0.f, nr1 = 0.f, nc0 = 0.f, nc1 = 0.f;
    if (t < 63) {
      nr0 = fwr_g[(t + 1) * HH + h0];
      nr1 = fwr_g[(t + 1) * HH + h0 + 16];
      nc0 = fw_g[(t + 1) * HH + h0];
      nc1 = fw_g[(t + 1) * HH + h0 + 16];
    }

    const f32x4 z4 = {0.f, 0.f, 0.f, 0.f};
    f32x4 a0 = z4, a1 = z4, a2 = z4, a3 = z4;
    __builtin_amdgcn_s_setprio(1);
#pragma unroll
    for (int kt = 0; kt < 8; ++kt) {
      a0 = __builtin_amdgcn_mfma_f32_16x16x32_bf16(Af[kt], Bf[kt][0], a0, 0, 0, 0);
      a2 = __builtin_amdgcn_mfma_f32_16x16x32_bf16(Af[kt], Bf[kt][2], a2, 0, 0, 0);
    }
#pragma unroll
    for (int kt = 0; kt < 8; ++kt) {
      a1 = __builtin_amdgcn_mfma_f32_16x16x32_bf16(Af[kt], Bf[kt][1], a1, 0, 0, 0);
      a3 = __builtin_amdgcn_mfma_f32_16x16x32_bf16(Af[kt], Bf[kt][3], a3, 0, 0, 0);
    }
    __builtin_amdgcn_s_setprio(0);

    const float g = attn_sT[t * 4 + q];  // 16-lane broadcast

    // cell 0 (needs a0,a2 only -> VALU overlaps a1/a3 MFMA pipe drain)
    const float yr0 = sel4(a0, q), yu0 = sel4(a2, q);
    const float r0 = 1.f / (1.f + __expf(-(fr0 + yr0)));
    const float x0 = fc0 + r0 * (yu0 + ub0);
    const float e0 = __expf(2.f * x0);
    const float h0t = 1.f - 2.f / (e0 + 1.f);
    cm0 += g * (h0t - cm0);

    // cell 1
    const float yr1 = sel4(a1, q), yu1 = sel4(a3, q);
    const float r1 = 1.f / (1.f + __expf(-(fr1 + yr1)));
    const float x1 = fc1 + r1 * (yu1 + ub1);
    const float e1 = __expf(2.f * x1);
    const float h1t = 1.f - 2.f / (e1 + 1.f);
    cm1 += g * (h1t - cm1);

    Cw[q * 136 + w * 16 + l15] = cvtpk(cm0, cm1);  // storage cols (2*l15, 2*l15+1)

    fr0 = nr0; fr1 = nr1; fc0 = nc0; fc1 = nc1;
    __syncthreads();  // single barrier: C writes complete before next Af reads
  }

  // final state in Cbf[0] (t=63 wrote buf 0); 4 rows x 128 dwords
  {
    const int row = tid >> 7, wo = tid & 127;
    ((unsigned int*)Cout)[(n * SS + i0 + row) * 128 + wo] =
        *(const unsigned int*)&Cbf[0][row * 272 + wo * 2];
  }
}

// ---------------------------------------------------------------------------
// Phase D: next_mem = relu([prevM | C | questions] @ nm_w^T + nm_b)
// Tile 64 rows x 32 cols -> 128 blocks.
// (cbf and nmbf's middle K-section share the same K permutation -> invariant)
// ---------------------------------------------------------------------------
__global__ __launch_bounds__(256) void next_mem_gemm(
    const unsigned short* __restrict__ pmbf, const unsigned short* __restrict__ cbf,
    const unsigned short* __restrict__ qbf, const unsigned short* __restrict__ nmbf,
    const float* __restrict__ nmb, float* __restrict__ out) {
  __shared__ unsigned short A[64][40];  // stride 40 bf16 (20 words -> 2-way max)
  const int bi = blockIdx.x;
  const int rb = bi >> 3, cb = bi & 7;
  const int r0 = rb * 64, c0 = cb * 32;
  const int tid = threadIdx.x, w = tid >> 6, l = tid & 63;
  const int l15 = l & 15, q = l >> 4;

  f32x4 acc[2];
  const f32x4 z4 = {0.f, 0.f, 0.f, 0.f};
#pragma unroll
  for (int nf = 0; nf < 2; ++nf) acc[nf] = z4;

  for (int kt = 0; kt < 24; ++kt) {
    const int kg = kt * 32;
    const unsigned short* src =
        kg < 256 ? (pmbf + kg) : (kg < 512 ? (cbf + kg - 256) : (qbf + kg - 512));
    const int kk = (tid & 15) * 2;
#pragma unroll
    for (int ps = 0; ps < 4; ++ps) {
      const int row = ps * 16 + (tid >> 4);
      *(unsigned int*)&A[row][kk] = *(const unsigned int*)(src + (r0 + row) * HH + kk);
    }
    __syncthreads();
    short8 Bfr[2];
#pragma unroll
    for (int nf = 0; nf < 2; ++nf)
      Bfr[nf] = *(const short8*)(nmbf + (c0 + nf * 16 + l15) * 768 + kg + q * 8);
    const short8 Af = *(const short8*)&A[w * 16 + l15][q * 8];
#pragma unroll
    for (int nf = 0; nf < 2; ++nf)
      acc[nf] = __builtin_amdgcn_mfma_f32_16x16x32_bf16(Af, Bfr[nf], acc[nf], 0, 0, 0);
    __syncthreads();
  }
#pragma unroll
  for (int nf = 0; nf < 2; ++nf) {
    const int col = c0 + nf * 16 + l15;
    const float bv = nmb[col];
#pragma unroll
    for (int v = 0; v < 4; ++v) {
      const int grow = r0 + w * 16 + q * 4 + v;
      out[grow * HH + col] = fmaxf(acc[nf][v] + bv, 0.f);
    }
  }
}

// ---------------------------------------------------------------------------
extern "C" void kernel_launch(void* const* d_in, const int* in_sizes, int n_in,
                              void* d_out, int out_size, void* d_ws, size_t ws_size,
                              hipStream_t stream) {
  const float* facts     = (const float*)d_in[0];
  const float* prevM     = (const float*)d_in[1];
  const float* questions = (const float*)d_in[2];
  const int*   doc_len   = (const int*)d_in[3];
  const float* z1w = (const float*)d_in[4];
  const float* z1b = (const float*)d_in[5];
  const float* z2w = (const float*)d_in[6];
  const float* z2b = (const float*)d_in[7];
  const float* Wrw = (const float*)d_in[8];
  const float* Wrb = (const float*)d_in[9];
  const float* Urw = (const float*)d_in[10];
  const float* Urb = (const float*)d_in[11];
  const float* Ww  = (const float*)d_in[12];
  const float* Wb  = (const float*)d_in[13];
  const float* Uw  = (const float*)d_in[14];
  const float* Ub  = (const float*)d_in[15];
  const float* nmw = (const float*)d_in[16];
  const float* nmb = (const float*)d_in[17];

  char* ws = (char*)d_ws;
  unsigned short* z1wbf  = (unsigned short*)(ws + 0);        // 512 KB
  unsigned short* wcatbf = (unsigned short*)(ws + 524288);   // 256 KB
  unsigned short* nmbf   = (unsigned short*)(ws + 786432);   // 384 KB
  unsigned short* pmbf   = (unsigned short*)(ws + 1179648);  // 512 KB
  unsigned short* qbf    = (unsigned short*)(ws + 1703936);  // 512 KB
  float* FWr = (float*)(ws + 2490368);                       // 1 MB
  float* FW  = (float*)(ws + 3538944);                       // 1 MB
  unsigned short* cbf = (unsigned short*)(ws + 4587520);     // 512 KB  (total ~4.9 MB)

  float* out  = (float*)d_out;
  float* attn = out + NB * SS * HH;  // second output region

  prolog_fused<<<800, 256, 0, stream>>>(z1w, Urw, Uw, nmw, prevM, questions,
                                        z1wbf, wcatbf, nmbf, pmbf, qbf,
                                        facts, Wrw, Wrb, Urb, Ww, Wb, FWr, FW);
  gate_gemm<<<512, 512, 0, stream>>>(facts, prevM, questions, z1wbf, z1b, z2w, z2b,
                                     doc_len, attn);
  gru_scan<<<256, 512, 0, stream>>>(wcatbf, FWr, FW, Ub, attn, cbf);
  next_mem_gemm<<<128, 256, 0, stream>>>(pmbf, cbf, qbf, nmbf, nmb, out);
}

// Round 8
// 242.055 us; speedup vs baseline: 1.1875x; 1.0177x over previous
//
#include <hip/hip_runtime.h>
#include <hip/hip_bf16.h>
#include <math.h>

#define NB 16
#define SS 64
#define HH 256
#define FAA 256

using short8 = __attribute__((ext_vector_type(8))) short;
using f32x4  = __attribute__((ext_vector_type(4))) float;

__device__ __forceinline__ unsigned int cvtpk(float a, float b) {
  unsigned int r;
  asm("v_cvt_pk_bf16_f32 %0, %1, %2" : "=v"(r) : "v"(a), "v"(b));  // RNE, a->lo b->hi
  return r;
}
// select a[q] without runtime vector indexing (dyn-indexed regs -> scratch)
__device__ __forceinline__ float sel4(const f32x4 a, int q) {
  const float s01 = (q & 1) ? a[1] : a[0];
  const float s23 = (q & 1) ? a[3] : a[2];
  return (q & 2) ? s23 : s01;
}

// ---------------------------------------------------------------------------
// Fused prolog, VECTORIZED: 8 elems/thread (2x float4 loads + 4x cvt_pk +
// one 16B store). Block map: [0,128) z1w | [128,192) wcat | [192,288) nmbf |
// [288,416) pm | [416,544) q | [544,800) fact_proj.
// wcat/nmbf K-PERMUTATION (storage (g*32+2l, g*32+2l+1) = actual cols
// (g*32+l, g*32+16+l)) vectorizes as two contiguous float4 gathers.
// gru_scan stores C in the same permuted order -> phase D invariant.
// ---------------------------------------------------------------------------
__global__ __launch_bounds__(256) void prolog_fused(
    const float* __restrict__ z1w, const float* __restrict__ Ur,
    const float* __restrict__ U, const float* __restrict__ nmw,
    const float* __restrict__ pm, const float* __restrict__ qs,
    unsigned short* __restrict__ z1wbf, unsigned short* __restrict__ wcatbf,
    unsigned short* __restrict__ nmbf, unsigned short* __restrict__ pmbf,
    unsigned short* __restrict__ qbf,
    const float* __restrict__ facts, const float* __restrict__ Wr,
    const float* __restrict__ Wrb, const float* __restrict__ Urb,
    const float* __restrict__ Ww, const float* __restrict__ Wb,
    float* __restrict__ FWr, float* __restrict__ FW) {
  __shared__ float fl[4][HH];
  const int bid = blockIdx.x, tid = threadIdx.x;

  auto cvt8 = [&](const float* src, unsigned short* dst, int base) {
    const float4 a = *(const float4*)(src + base);
    const float4 b = *(const float4*)(src + base + 4);
    uint4 o;
    o.x = cvtpk(a.x, a.y); o.y = cvtpk(a.z, a.w);
    o.z = cvtpk(b.x, b.y); o.w = cvtpk(b.z, b.w);
    *(uint4*)(dst + base) = o;  // base mult of 8 -> 16B aligned
  };
  // permuted pair-pack: storage u32 w holds (row[c0+w], row[c0+16+w])
  auto cvt8perm = [&](const float* row, unsigned short* dst, int sbase, int c0) {
    const float4 lo = *(const float4*)(row + c0);
    const float4 hi = *(const float4*)(row + c0 + 16);
    uint4 o;
    o.x = cvtpk(lo.x, hi.x); o.y = cvtpk(lo.y, hi.y);
    o.z = cvtpk(lo.z, hi.z); o.w = cvtpk(lo.w, hi.w);
    *(uint4*)(dst + sbase) = o;
  };

  if (bid < 128) {               // z1w: 262144 elems
    const int base = (bid * 256 + tid) * 8;
    cvt8(z1w, z1wbf, base);
    return;
  }
  if (bid < 192) {               // wcat: 131072 elems, K-permuted
    const int base = ((bid - 128) * 256 + tid) * 8;
    const int o = base >> 8, s0 = base & 255;
    const int gb = s0 & ~31, t0 = s0 & 31;          // t0 in {0,8,16,24}
    const float* row = (o < 256) ? (Ur + o * 256) : (U + (o - 256) * 256);
    cvt8perm(row, wcatbf, base, gb + (t0 >> 1));
    return;
  }
  if (bid < 288) {               // nmbf: 196608 elems, middle section permuted
    const int base = ((bid - 192) * 256 + tid) * 8;
    const int o = base / 768, k0 = base - o * 768;
    const float* row = nmw + o * 768;
    if (k0 >= 256 && k0 < 512) {
      const int s0 = k0 - 256, gb = s0 & ~31, t0 = s0 & 31;
      cvt8perm(row, nmbf, base, 256 + gb + (t0 >> 1));
    } else {
      cvt8(row, nmbf + o * 768, k0);
    }
    return;
  }
  if (bid < 416) {               // prevM: 262144 elems
    const int base = ((bid - 288) * 256 + tid) * 8;
    cvt8(pm, pmbf, base);
    return;
  }
  if (bid < 544) {               // questions: 262144 elems
    const int base = ((bid - 416) * 256 + tid) * 8;
    cvt8(qs, qbf, base);
    return;
  }
  // ---- fact_proj: FWr[b,h] = facts[b]·Wr[h]+Wr_b[h]+Ur_b[h]; FW = facts[b]·W[h]+W_b[h]
  const int b0 = (bid - 544) * 4;
#pragma unroll
  for (int r = 0; r < 4; ++r) fl[r][tid] = facts[(b0 + r) * HH + tid];
  __syncthreads();
  float ar[4] = {0.f, 0.f, 0.f, 0.f}, aw[4] = {0.f, 0.f, 0.f, 0.f};
  const float4* wr = (const float4*)(Wr + tid * HH);
  const float4* ww = (const float4*)(Ww + tid * HH);
  for (int d4 = 0; d4 < 64; ++d4) {
    float4 a = wr[d4], b = ww[d4];
#pragma unroll
    for (int r = 0; r < 4; ++r) {
      float4 f = *(const float4*)&fl[r][d4 * 4];  // LDS broadcast
      ar[r] += a.x * f.x + a.y * f.y + a.z * f.z + a.w * f.w;
      aw[r] += b.x * f.x + b.y * f.y + b.z * f.z + b.w * f.w;
    }
  }
  const float br = Wrb[tid] + Urb[tid], bw = Wb[tid];
#pragma unroll
  for (int r = 0; r < 4; ++r) {
    FWr[(b0 + r) * HH + tid] = ar[r] + br;
    FW[(b0 + r) * HH + tid] = aw[r] + bw;
  }
}

// ---------------------------------------------------------------------------
// Phase A: gate GEMM + FUSED masked softmax. Block = (n, 2 i's) = 128 rows,
// 256 cols, K=1024 as 32 chunks of 32 (c = hc*4+s; accumulation order
// bit-identical to prior rounds).
// T3/T4 counted-vmcnt: TRIPLE-buffered (74KB LDS, 2 blocks/CU), staging
// chunk c+2 during phase c, raw "s_waitcnt vmcnt(N) lgkmcnt(0); s_barrier":
// N=2 steady (2 loads/stage in flight), N=8 on phases that also issue the 6
// f/q/m prefetch loads, N=0 at c=30 (last staged chunk). Loop fully unrolled
// so buf indices / N fold at compile time; barriers are uniform (no deadlock).
// ---------------------------------------------------------------------------
__global__ __launch_bounds__(512, 4) void gate_gemm(
    const float* __restrict__ facts, const float* __restrict__ prevM,
    const float* __restrict__ questions, const unsigned short* __restrict__ z1wbf,
    const float* __restrict__ z1b, const float* __restrict__ z2w,
    const float* __restrict__ z2b, const int* __restrict__ doc_len,
    float* __restrict__ attn) {
  __shared__ unsigned short Ab[3][128 * 32];  // 8KB per buf
  __shared__ unsigned short Bb[3][256 * 32];  // 16KB per buf
  __shared__ float Gpart[128][4];

  const int bi = blockIdx.x;
  const int n = bi >> 5, i0 = (bi & 31) * 2;
  const int tid = threadIdx.x;
  const int w = tid >> 6, l = tid & 63;
  const int rg = w >> 2, cg = w & 3;        // rowgroup (2), colgroup (4)
  const int l15 = l & 15, q = l >> 4;
  const int t15 = tid & 15, jb = tid >> 4;  // builder mapping (jb 0..31)

  const float* fn = facts + n * SS * HH;
  const float* qn = questions + (n * SS + i0) * HH;
  const float* mn = prevM + (n * SS + i0) * HH;

  // stage B chunk c into Bb[buf]: wave w covers cols w*32..w*32+31; 2 loads/wave
  auto stageB = [&](int buf, int c) {
    const int kb = (c & 3) * 256 + (c >> 2) * 32;
    const int swz = ((l & 3) ^ ((l >> 2) & 3)) * 8;  // colg&3 == (l>>2)&3
#pragma unroll
    for (int j = 0; j < 2; ++j) {
      const int colg = w * 32 + j * 16 + (l >> 2);
      const unsigned short* src = z1wbf + colg * 1024 + kb + swz;
      __builtin_amdgcn_global_load_lds(src, Bb[buf] + (w * 32 + j * 16) * 32, 16, 0, 0);
    }
  };

  auto buildA = [&](int buf, int s, float2 f0, float2 f1, float2 q0, float2 q1,
                    float2 m0, float2 m1) {
    unsigned int* dst = (unsigned int*)Ab[buf];
    const int dsw = t15 ^ ((jb & 3) << 2);  // swizzled 4B-slot (row&3 == jb&3)
    const float2 o0 = (s & 1) ? m0 : q0;
    const float2 o1 = (s & 1) ? m1 : q1;
#pragma unroll
    for (int pl = 0; pl < 2; ++pl) {
      const float fx = pl ? f1.x : f0.x;
      const float fy = pl ? f1.y : f0.y;
#pragma unroll
      for (int il = 0; il < 2; ++il) {
        const int row = il * 64 + pl * 32 + jb;
        const float ox = il ? o1.x : o0.x;
        const float oy = il ? o1.y : o0.y;
        float a, b;
        if (s < 2) { a = fx * ox;         b = fy * oy; }
        else       { a = fabsf(fx - ox);  b = fabsf(fy - oy); }
        dst[row * 16 + dsw] = cvtpk(a, b);
      }
    }
  };

  const f32x4 zero4 = {0.f, 0.f, 0.f, 0.f};
  f32x4 acc[4][4];
#pragma unroll
  for (int a = 0; a < 4; ++a)
#pragma unroll
    for (int b = 0; b < 4; ++b) acc[a][b] = zero4;

  auto mfmaStep = [&](int buf) {
    short8 Bfr[4];
#pragma unroll
    for (int nf = 0; nf < 4; ++nf) {
      const int col = cg * 64 + nf * 16 + l15;
      Bfr[nf] = *(const short8*)&Bb[buf][col * 32 + (q ^ (l15 & 3)) * 8];
    }
    __builtin_amdgcn_s_setprio(1);
#pragma unroll
    for (int mf = 0; mf < 4; ++mf) {
      const int row = rg * 64 + mf * 16 + l15;
      const short8 Afm = *(const short8*)&Ab[buf][row * 32 + (q ^ (l15 & 3)) * 8];
#pragma unroll
      for (int nf = 0; nf < 4; ++nf)
        acc[mf][nf] = __builtin_amdgcn_mfma_f32_16x16x32_bf16(Afm, Bfr[nf], acc[mf][nf], 0, 0, 0);
    }
    __builtin_amdgcn_s_setprio(0);
  };

  const int hh2 = t15 * 2;
  auto pf = [&](int hc, float2& f0, float2& f1, float2& q0, float2& q1,
                float2& m0, float2& m1) {
    const int h = hc * 32 + hh2;
    f0 = *(const float2*)(fn + jb * HH + h);
    f1 = *(const float2*)(fn + (jb + 32) * HH + h);
    q0 = *(const float2*)(qn + h);
    q1 = *(const float2*)(qn + HH + h);
    m0 = *(const float2*)(mn + h);
    m1 = *(const float2*)(mn + HH + h);
  };

  float2 Rf0, Rf1, Rq0, Rq1, Rm0, Rm1;    // current hc operands
  float2 Sf0, Sf1, Sq0, Sq1, Sm0, Sm1;    // next hc operands
  pf(0, Rf0, Rf1, Rq0, Rq1, Rm0, Rm1);
  stageB(0, 0);  // chunk 0 -> buf 0
  stageB(1, 1);  // chunk 1 -> buf 1
  buildA(0, 0, Rf0, Rf1, Rq0, Rq1, Rm0, Rm1);
  // outstanding: chunk0(2) + chunk1(2); need chunk0 landed -> vmcnt(2)
  asm volatile("s_waitcnt vmcnt(2) lgkmcnt(0)\n\ts_barrier" ::: "memory");

#pragma unroll
  for (int c = 0; c < 32; ++c) {
    const int s = c & 3, hc = c >> 2;
    const int cb = c % 3, nb2 = (c + 1) % 3, fb = (c + 2) % 3;
    const bool pfphase = (s == 2) && (hc < 7);

    if (c + 2 < 32) stageB(fb, c + 2);
    if (pfphase) pf(hc + 1, Sf0, Sf1, Sq0, Sq1, Sm0, Sm1);
    if (c + 1 < 32) {
      if (((c + 1) & 3) == 0)
        buildA(nb2, 0, Sf0, Sf1, Sq0, Sq1, Sm0, Sm1);
      else
        buildA(nb2, (c + 1) & 3, Rf0, Rf1, Rq0, Rq1, Rm0, Rm1);
    }
    mfmaStep(cb);

    // counted-vmcnt barrier: ensure chunk c+1's 2 stage loads landed, leave
    // chunk c+2's (and any pf loads) in flight. Loads younger than chunk c+1's
    // stage: 2 (stage c+2) [+6 pf on pf-phases]. c==30: nothing younger -> 0.
    if (c <= 29) {
      if (pfphase)
        asm volatile("s_waitcnt vmcnt(8) lgkmcnt(0)\n\ts_barrier" ::: "memory");
      else
        asm volatile("s_waitcnt vmcnt(2) lgkmcnt(0)\n\ts_barrier" ::: "memory");
    } else if (c == 30) {
      asm volatile("s_waitcnt vmcnt(0) lgkmcnt(0)\n\ts_barrier" ::: "memory");
    }
    if (s == 3) {
      Rf0 = Sf0; Rf1 = Sf1; Rq0 = Sq0; Rq1 = Sq1; Rm0 = Sm0; Rm1 = Sm1;
    }
  }

  // epilogue: tanh, scale by z2_w, reduce over k
  float psum[4][4];
#pragma unroll
  for (int mf = 0; mf < 4; ++mf)
#pragma unroll
    for (int v = 0; v < 4; ++v) psum[mf][v] = 0.f;

#pragma unroll
  for (int nf = 0; nf < 4; ++nf) {
    const int k = cg * 64 + nf * 16 + l15;
    const float zb = z1b[k], zw = z2w[k];
#pragma unroll
    for (int mf = 0; mf < 4; ++mf)
#pragma unroll
      for (int v = 0; v < 4; ++v) {
        const float x = acc[mf][nf][v] + zb;
        const float e = __expf(2.f * x);
        const float t = 1.f - 2.f / (e + 1.f);  // tanh(x)
        psum[mf][v] += zw * t;
      }
  }
#pragma unroll
  for (int d = 1; d < 16; d <<= 1)
#pragma unroll
    for (int mf = 0; mf < 4; ++mf)
#pragma unroll
      for (int v = 0; v < 4; ++v) psum[mf][v] += __shfl_xor(psum[mf][v], d, 64);
  if (l15 == 0) {
#pragma unroll
    for (int mf = 0; mf < 4; ++mf)
#pragma unroll
      for (int v = 0; v < 4; ++v)
        Gpart[rg * 64 + mf * 16 + q * 4 + v][cg] = psum[mf][v];
  }
  __syncthreads();
  if (tid < 128) {  // waves 0,1 fully active: wave = row i, lane = j
    const float gg = Gpart[tid][0] + Gpart[tid][1] + Gpart[tid][2] + Gpart[tid][3] + z2b[0];
    const int i = i0 + (tid >> 6), j = tid & 63;
    const int dl = doc_len[n];
    const float x = (j < dl && gg != 0.0f) ? gg : -INFINITY;  // where(G*mask==0,-inf)
    float mx = x;
#pragma unroll
    for (int d = 1; d < 64; d <<= 1) mx = fmaxf(mx, __shfl_xor(mx, d, 64));
    const float e = (x == -INFINITY) ? 0.f : __expf(x - mx);
    float s = e;
#pragma unroll
    for (int d = 1; d < 64; d <<= 1) s += __shfl_xor(s, d, 64);
    attn[(n * SS + i) * SS + j] = e / s;
  }
}

// ---------------------------------------------------------------------------
// Phase C: GRU-style scan. Block = (n, 4 rows), 256 blocks = all 256 CUs.
// (proven round-4/6 version, 72.6us; near its structural floor ~66us)
// Rows dup'd 4x in M=16 (broadcast A-read); lane (q,l15) updates row q only.
// ---------------------------------------------------------------------------
__global__ __launch_bounds__(512, 2) void gru_scan(
    const unsigned short* __restrict__ wcat, const float* __restrict__ FWr,
    const float* __restrict__ FW, const float* __restrict__ Ub,
    const float* __restrict__ attn, unsigned short* __restrict__ Cout) {
  __shared__ unsigned short Cbf[2][4 * 272];  // stride 272 sh (136 dw, 8 mod 32 -> 2-way)
  __shared__ float attn_sT[64 * 4];           // [t][row]

  const int bi = blockIdx.x, n = bi >> 4, i0 = (bi & 15) * 4;
  const int tid = threadIdx.x, w = tid >> 6, l = tid & 63;
  const int l15 = l & 15, q = l >> 4;
  const int h0 = w * 32 + l15;  // lane's actual h cols: h0 and h0+16

  // persistent B-fragments: f=0/1 -> Ur cols h0/h0+16 ; f=2/3 -> U cols (K perm'd)
  short8 Bf[8][4];
#pragma unroll
  for (int f = 0; f < 4; ++f) {
    const int wrow = ((f >> 1) ? 256 : 0) + w * 32 + (f & 1) * 16 + l15;
    const unsigned short* bb = wcat + wrow * 256 + q * 8;
#pragma unroll
    for (int kt = 0; kt < 8; ++kt)
      Bf[kt][f] = *(const short8*)(bb + kt * 32);
  }

  const float ub0 = Ub[h0], ub1 = Ub[h0 + 16];

  for (int e = tid; e < 64 * 4; e += 512)  // attn transposed: [t][row]
    attn_sT[e] = attn[(n * SS + i0 + (e & 3)) * SS + (e >> 2)];
  for (int e = tid; e < 544; e += 512)
    ((unsigned int*)Cbf[0])[e] = 0u;
  __syncthreads();

  const float* fwr_g = FWr + n * SS * HH;
  const float* fw_g  = FW + n * SS * HH;

  float cm0 = 0.f, cm1 = 0.f;  // fp32 master state: (row q, h0) and (row q, h0+16)
  float fr0 = fwr_g[h0], fr1 = fwr_g[h0 + 16];
  float fc0 = fw_g[h0],  fc1 = fw_g[h0 + 16];

  for (int t = 0; t < 64; ++t) {
    const int cur = t & 1;
    const unsigned short* Cr = Cbf[cur];
    unsigned int* Cw = (unsigned int*)Cbf[cur ^ 1];

    // A-fragments: row (l15&3) -> 4-way broadcast read
    short8 Af[8];
    const int arow = (l15 & 3) * 272;
#pragma unroll
    for (int kt = 0; kt < 8; ++kt)
      Af[kt] = *(const short8*)&Cr[arow + kt * 32 + q * 8];

    // prefetch next step's FWr/FW (consumed next iteration -> latency hidden)
    float nr0 = 0.f, nr1 = 0.f, nc0 = 0.f, nc1 = 0.f;
    if (t < 63) {
      nr0 = fwr_g[(t + 1) * HH + h0];
      nr1 = fwr_g[(t + 1) * HH + h0 + 16];
      nc0 = fw_g[(t + 1) * HH + h0];
      nc1 = fw_g[(t + 1) * HH + h0 + 16];
    }

    const f32x4 z4 = {0.f, 0.f, 0.f, 0.f};
    f32x4 a0 = z4, a1 = z4, a2 = z4, a3 = z4;
    __builtin_amdgcn_s_setprio(1);
#pragma unroll
    for (int kt = 0; kt < 8; ++kt) {
      a0 = __builtin_amdgcn_mfma_f32_16x16x32_bf16(Af[kt], Bf[kt][0], a0, 0, 0, 0);
      a2 = __builtin_amdgcn_mfma_f32_16x16x32_bf16(Af[kt], Bf[kt][2], a2, 0, 0, 0);
    }
#pragma unroll
    for (int kt = 0; kt < 8; ++kt) {
      a1 = __builtin_amdgcn_mfma_f32_16x16x32_bf16(Af[kt], Bf[kt][1], a1, 0, 0, 0);
      a3 = __builtin_amdgcn_mfma_f32_16x16x32_bf16(Af[kt], Bf[kt][3], a3, 0, 0, 0);
    }
    __builtin_amdgcn_s_setprio(0);

    const float g = attn_sT[t * 4 + q];  // 16-lane broadcast

    // cell 0 (needs a0,a2 only -> VALU overlaps a1/a3 MFMA pipe drain)
    const float yr0 = sel4(a0, q), yu0 = sel4(a2, q);
    const float r0 = 1.f / (1.f + __expf(-(fr0 + yr0)));
    const float x0 = fc0 + r0 * (yu0 + ub0);
    const float e0 = __expf(2.f * x0);
    const float h0t = 1.f - 2.f / (e0 + 1.f);
    cm0 += g * (h0t - cm0);

    // cell 1
    const float yr1 = sel4(a1, q), yu1 = sel4(a3, q);
    const float r1 = 1.f / (1.f + __expf(-(fr1 + yr1)));
    const float x1 = fc1 + r1 * (yu1 + ub1);
    const float e1 = __expf(2.f * x1);
    const float h1t = 1.f - 2.f / (e1 + 1.f);
    cm1 += g * (h1t - cm1);

    Cw[q * 136 + w * 16 + l15] = cvtpk(cm0, cm1);  // storage cols (2*l15, 2*l15+1)

    fr0 = nr0; fr1 = nr1; fc0 = nc0; fc1 = nc1;
    __syncthreads();  // single barrier: C writes complete before next Af reads
  }

  // final state in Cbf[0] (t=63 wrote buf 0); 4 rows x 128 dwords
  {
    const int row = tid >> 7, wo = tid & 127;
    ((unsigned int*)Cout)[(n * SS + i0 + row) * 128 + wo] =
        *(const unsigned int*)&Cbf[0][row * 272 + wo * 2];
  }
}

// ---------------------------------------------------------------------------
// Phase D: next_mem = relu([prevM | C | questions] @ nm_w^T + nm_b)
// Tile 64 rows x 32 cols -> 128 blocks.
// (cbf and nmbf's middle K-section share the same K permutation -> invariant)
// ---------------------------------------------------------------------------
__global__ __launch_bounds__(256) void next_mem_gemm(
    const unsigned short* __restrict__ pmbf, const unsigned short* __restrict__ cbf,
    const unsigned short* __restrict__ qbf, const unsigned short* __restrict__ nmbf,
    const float* __restrict__ nmb, float* __restrict__ out) {
  __shared__ unsigned short A[64][40];  // stride 40 bf16 (20 words -> 2-way max)
  const int bi = blockIdx.x;
  const int rb = bi >> 3, cb = bi & 7;
  const int r0 = rb * 64, c0 = cb * 32;
  const int tid = threadIdx.x, w = tid >> 6, l = tid & 63;
  const int l15 = l & 15, q = l >> 4;

  f32x4 acc[2];
  const f32x4 z4 = {0.f, 0.f, 0.f, 0.f};
#pragma unroll
  for (int nf = 0; nf < 2; ++nf) acc[nf] = z4;

  for (int kt = 0; kt < 24; ++kt) {
    const int kg = kt * 32;
    const unsigned short* src =
        kg < 256 ? (pmbf + kg) : (kg < 512 ? (cbf + kg - 256) : (qbf + kg - 512));
    const int kk = (tid & 15) * 2;
#pragma unroll
    for (int ps = 0; ps < 4; ++ps) {
      const int row = ps * 16 + (tid >> 4);
      *(unsigned int*)&A[row][kk] = *(const unsigned int*)(src + (r0 + row) * HH + kk);
    }
    __syncthreads();
    short8 Bfr[2];
#pragma unroll
    for (int nf = 0; nf < 2; ++nf)
      Bfr[nf] = *(const short8*)(nmbf + (c0 + nf * 16 + l15) * 768 + kg + q * 8);
    const short8 Af = *(const short8*)&A[w * 16 + l15][q * 8];
#pragma unroll
    for (int nf = 0; nf < 2; ++nf)
      acc[nf] = __builtin_amdgcn_mfma_f32_16x16x32_bf16(Af, Bfr[nf], acc[nf], 0, 0, 0);
    __syncthreads();
  }
#pragma unroll
  for (int nf = 0; nf < 2; ++nf) {
    const int col = c0 + nf * 16 + l15;
    const float bv = nmb[col];
#pragma unroll
    for (int v = 0; v < 4; ++v) {
      const int grow = r0 + w * 16 + q * 4 + v;
      out[grow * HH + col] = fmaxf(acc[nf][v] + bv, 0.f);
    }
  }
}

// ---------------------------------------------------------------------------
extern "C" void kernel_launch(void* const* d_in, const int* in_sizes, int n_in,
                              void* d_out, int out_size, void* d_ws, size_t ws_size,
                              hipStream_t stream) {
  const float* facts     = (const float*)d_in[0];
  const float* prevM     = (const float*)d_in[1];
  const float* questions = (const float*)d_in[2];
  const int*   doc_len   = (const int*)d_in[3];
  const float* z1w = (const float*)d_in[4];
  const float* z1b = (const float*)d_in[5];
  const float* z2w = (const float*)d_in[6];
  const float* z2b = (const float*)d_in[7];
  const float* Wrw = (const float*)d_in[8];
  const float* Wrb = (const float*)d_in[9];
  const float* Urw = (const float*)d_in[10];
  const float* Urb = (const float*)d_in[11];
  const float* Ww  = (const float*)d_in[12];
  const float* Wb  = (const float*)d_in[13];
  const float* Uw  = (const float*)d_in[14];
  const float* Ub  = (const float*)d_in[15];
  const float* nmw = (const float*)d_in[16];
  const float* nmb = (const float*)d_in[17];

  char* ws = (char*)d_ws;
  unsigned short* z1wbf  = (unsigned short*)(ws + 0);        // 512 KB
  unsigned short* wcatbf = (unsigned short*)(ws + 524288);   // 256 KB
  unsigned short* nmbf   = (unsigned short*)(ws + 786432);   // 384 KB
  unsigned short* pmbf   = (unsigned short*)(ws + 1179648);  // 512 KB
  unsigned short* qbf    = (unsigned short*)(ws + 1703936);  // 512 KB
  float* FWr = (float*)(ws + 2490368);                       // 1 MB
  float* FW  = (float*)(ws + 3538944);                       // 1 MB
  unsigned short* cbf = (unsigned short*)(ws + 4587520);     // 512 KB  (total ~4.9 MB)

  float* out  = (float*)d_out;
  float* attn = out + NB * SS * HH;  // second output region

  prolog_fused<<<800, 256, 0, stream>>>(z1w, Urw, Uw, nmw, prevM, questions,
                                        z1wbf, wcatbf, nmbf, pmbf, qbf,
                                        facts, Wrw, Wrb, Urb, Ww, Wb, FWr, FW);
  gate_gemm<<<512, 512, 0, stream>>>(facts, prevM, questions, z1wbf, z1b, z2w, z2b,
                                     doc_len, attn);
  gru_scan<<<256, 512, 0, stream>>>(wcatbf, FWr, FW, Ub, attn, cbf);
  next_mem_gemm<<<128, 256, 0, stream>>>(pmbf, cbf, qbf, nmbf, nmb, out);
}

// Round 9
// 241.129 us; speedup vs baseline: 1.1920x; 1.0038x over previous
//
#include <hip/hip_runtime.h>
#include <hip/hip_bf16.h>
#include <math.h>

#define NB 16
#define SS 64
#define HH 256
#define FAA 256

using short8 = __attribute__((ext_vector_type(8))) short;
using f32x4  = __attribute__((ext_vector_type(4))) float;

__device__ __forceinline__ unsigned int cvtpk(float a, float b) {
  unsigned int r;
  asm("v_cvt_pk_bf16_f32 %0, %1, %2" : "=v"(r) : "v"(a), "v"(b));  // RNE, a->lo b->hi
  return r;
}
// select a[q] without runtime vector indexing (dyn-indexed regs -> scratch)
__device__ __forceinline__ float sel4(const f32x4 a, int q) {
  const float s01 = (q & 1) ? a[1] : a[0];
  const float s23 = (q & 1) ? a[3] : a[2];
  return (q & 2) ? s23 : s01;
}

// ---------------------------------------------------------------------------
// Fused prolog, VECTORIZED: 8 elems/thread (2x float4 loads + 4x cvt_pk +
// one 16B store). Block map: [0,128) z1w | [128,192) wcat | [192,288) nmbf |
// [288,416) pm | [416,544) q | [544,800) fact_proj.
// wcat/nmbf K-PERMUTATION (storage (g*32+2l, g*32+2l+1) = actual cols
// (g*32+l, g*32+16+l)) vectorizes as two contiguous float4 gathers.
// gru_scan stores C in the same permuted order -> phase D invariant.
// ---------------------------------------------------------------------------
__global__ __launch_bounds__(256) void prolog_fused(
    const float* __restrict__ z1w, const float* __restrict__ Ur,
    const float* __restrict__ U, const float* __restrict__ nmw,
    const float* __restrict__ pm, const float* __restrict__ qs,
    unsigned short* __restrict__ z1wbf, unsigned short* __restrict__ wcatbf,
    unsigned short* __restrict__ nmbf, unsigned short* __restrict__ pmbf,
    unsigned short* __restrict__ qbf,
    const float* __restrict__ facts, const float* __restrict__ Wr,
    const float* __restrict__ Wrb, const float* __restrict__ Urb,
    const float* __restrict__ Ww, const float* __restrict__ Wb,
    float* __restrict__ FWr, float* __restrict__ FW) {
  __shared__ float fl[4][HH];
  const int bid = blockIdx.x, tid = threadIdx.x;

  auto cvt8 = [&](const float* src, unsigned short* dst, int base) {
    const float4 a = *(const float4*)(src + base);
    const float4 b = *(const float4*)(src + base + 4);
    uint4 o;
    o.x = cvtpk(a.x, a.y); o.y = cvtpk(a.z, a.w);
    o.z = cvtpk(b.x, b.y); o.w = cvtpk(b.z, b.w);
    *(uint4*)(dst + base) = o;  // base mult of 8 -> 16B aligned
  };
  // permuted pair-pack: storage u32 w holds (row[c0+w], row[c0+16+w])
  auto cvt8perm = [&](const float* row, unsigned short* dst, int sbase, int c0) {
    const float4 lo = *(const float4*)(row + c0);
    const float4 hi = *(const float4*)(row + c0 + 16);
    uint4 o;
    o.x = cvtpk(lo.x, hi.x); o.y = cvtpk(lo.y, hi.y);
    o.z = cvtpk(lo.z, hi.z); o.w = cvtpk(lo.w, hi.w);
    *(uint4*)(dst + sbase) = o;
  };

  if (bid < 128) {               // z1w: 262144 elems
    const int base = (bid * 256 + tid) * 8;
    cvt8(z1w, z1wbf, base);
    return;
  }
  if (bid < 192) {               // wcat: 131072 elems, K-permuted
    const int base = ((bid - 128) * 256 + tid) * 8;
    const int o = base >> 8, s0 = base & 255;
    const int gb = s0 & ~31, t0 = s0 & 31;          // t0 in {0,8,16,24}
    const float* row = (o < 256) ? (Ur + o * 256) : (U + (o - 256) * 256);
    cvt8perm(row, wcatbf, base, gb + (t0 >> 1));
    return;
  }
  if (bid < 288) {               // nmbf: 196608 elems, middle section permuted
    const int base = ((bid - 192) * 256 + tid) * 8;
    const int o = base / 768, k0 = base - o * 768;
    const float* row = nmw + o * 768;
    if (k0 >= 256 && k0 < 512) {
      const int s0 = k0 - 256, gb = s0 & ~31, t0 = s0 & 31;
      cvt8perm(row, nmbf, base, 256 + gb + (t0 >> 1));
    } else {
      cvt8(row, nmbf + o * 768, k0);
    }
    return;
  }
  if (bid < 416) {               // prevM: 262144 elems
    const int base = ((bid - 288) * 256 + tid) * 8;
    cvt8(pm, pmbf, base);
    return;
  }
  if (bid < 544) {               // questions: 262144 elems
    const int base = ((bid - 416) * 256 + tid) * 8;
    cvt8(qs, qbf, base);
    return;
  }
  // ---- fact_proj: FWr[b,h] = facts[b]·Wr[h]+Wr_b[h]+Ur_b[h]; FW = facts[b]·W[h]+W_b[h]
  const int b0 = (bid - 544) * 4;
#pragma unroll
  for (int r = 0; r < 4; ++r) fl[r][tid] = facts[(b0 + r) * HH + tid];
  __syncthreads();
  float ar[4] = {0.f, 0.f, 0.f, 0.f}, aw[4] = {0.f, 0.f, 0.f, 0.f};
  const float4* wr = (const float4*)(Wr + tid * HH);
  const float4* ww = (const float4*)(Ww + tid * HH);
  for (int d4 = 0; d4 < 64; ++d4) {
    float4 a = wr[d4], b = ww[d4];
#pragma unroll
    for (int r = 0; r < 4; ++r) {
      float4 f = *(const float4*)&fl[r][d4 * 4];  // LDS broadcast
      ar[r] += a.x * f.x + a.y * f.y + a.z * f.z + a.w * f.w;
      aw[r] += b.x * f.x + b.y * f.y + b.z * f.z + b.w * f.w;
    }
  }
  const float br = Wrb[tid] + Urb[tid], bw = Wb[tid];
#pragma unroll
  for (int r = 0; r < 4; ++r) {
    FWr[(b0 + r) * HH + tid] = ar[r] + br;
    FW[(b0 + r) * HH + tid] = aw[r] + bw;
  }
}

// ---------------------------------------------------------------------------
// Phase A: gate GEMM + FUSED masked softmax. Block = (n, 2 i's) = 128 rows,
// 256 cols, K=1024 as 32 chunks of 32 (c = hc*4+s; accumulation order
// bit-identical to prior rounds).
// T3/T4 counted-vmcnt: TRIPLE-buffered (74KB LDS, 2 blocks/CU), staging
// chunk c+2 during phase c, raw "s_waitcnt vmcnt(N) lgkmcnt(0); s_barrier":
// N=2 steady, N=8 on f/q/m-prefetch phases, N=0 at c=30. Verified r8.
// ---------------------------------------------------------------------------
__global__ __launch_bounds__(512, 4) void gate_gemm(
    const float* __restrict__ facts, const float* __restrict__ prevM,
    const float* __restrict__ questions, const unsigned short* __restrict__ z1wbf,
    const float* __restrict__ z1b, const float* __restrict__ z2w,
    const float* __restrict__ z2b, const int* __restrict__ doc_len,
    float* __restrict__ attn) {
  __shared__ unsigned short Ab[3][128 * 32];  // 8KB per buf
  __shared__ unsigned short Bb[3][256 * 32];  // 16KB per buf
  __shared__ float Gpart[128][4];

  const int bi = blockIdx.x;
  const int n = bi >> 5, i0 = (bi & 31) * 2;
  const int tid = threadIdx.x;
  const int w = tid >> 6, l = tid & 63;
  const int rg = w >> 2, cg = w & 3;        // rowgroup (2), colgroup (4)
  const int l15 = l & 15, q = l >> 4;
  const int t15 = tid & 15, jb = tid >> 4;  // builder mapping (jb 0..31)

  const float* fn = facts + n * SS * HH;
  const float* qn = questions + (n * SS + i0) * HH;
  const float* mn = prevM + (n * SS + i0) * HH;

  // stage B chunk c into Bb[buf]: wave w covers cols w*32..w*32+31; 2 loads/wave
  auto stageB = [&](int buf, int c) {
    const int kb = (c & 3) * 256 + (c >> 2) * 32;
    const int swz = ((l & 3) ^ ((l >> 2) & 3)) * 8;  // colg&3 == (l>>2)&3
#pragma unroll
    for (int j = 0; j < 2; ++j) {
      const int colg = w * 32 + j * 16 + (l >> 2);
      const unsigned short* src = z1wbf + colg * 1024 + kb + swz;
      __builtin_amdgcn_global_load_lds(src, Bb[buf] + (w * 32 + j * 16) * 32, 16, 0, 0);
    }
  };

  auto buildA = [&](int buf, int s, float2 f0, float2 f1, float2 q0, float2 q1,
                    float2 m0, float2 m1) {
    unsigned int* dst = (unsigned int*)Ab[buf];
    const int dsw = t15 ^ ((jb & 3) << 2);  // swizzled 4B-slot (row&3 == jb&3)
    const float2 o0 = (s & 1) ? m0 : q0;
    const float2 o1 = (s & 1) ? m1 : q1;
#pragma unroll
    for (int pl = 0; pl < 2; ++pl) {
      const float fx = pl ? f1.x : f0.x;
      const float fy = pl ? f1.y : f0.y;
#pragma unroll
      for (int il = 0; il < 2; ++il) {
        const int row = il * 64 + pl * 32 + jb;
        const float ox = il ? o1.x : o0.x;
        const float oy = il ? o1.y : o0.y;
        float a, b;
        if (s < 2) { a = fx * ox;         b = fy * oy; }
        else       { a = fabsf(fx - ox);  b = fabsf(fy - oy); }
        dst[row * 16 + dsw] = cvtpk(a, b);
      }
    }
  };

  const f32x4 zero4 = {0.f, 0.f, 0.f, 0.f};
  f32x4 acc[4][4];
#pragma unroll
  for (int a = 0; a < 4; ++a)
#pragma unroll
    for (int b = 0; b < 4; ++b) acc[a][b] = zero4;

  auto mfmaStep = [&](int buf) {
    short8 Bfr[4];
#pragma unroll
    for (int nf = 0; nf < 4; ++nf) {
      const int col = cg * 64 + nf * 16 + l15;
      Bfr[nf] = *(const short8*)&Bb[buf][col * 32 + (q ^ (l15 & 3)) * 8];
    }
    __builtin_amdgcn_s_setprio(1);
#pragma unroll
    for (int mf = 0; mf < 4; ++mf) {
      const int row = rg * 64 + mf * 16 + l15;
      const short8 Afm = *(const short8*)&Ab[buf][row * 32 + (q ^ (l15 & 3)) * 8];
#pragma unroll
      for (int nf = 0; nf < 4; ++nf)
        acc[mf][nf] = __builtin_amdgcn_mfma_f32_16x16x32_bf16(Afm, Bfr[nf], acc[mf][nf], 0, 0, 0);
    }
    __builtin_amdgcn_s_setprio(0);
  };

  const int hh2 = t15 * 2;
  auto pf = [&](int hc, float2& f0, float2& f1, float2& q0, float2& q1,
                float2& m0, float2& m1) {
    const int h = hc * 32 + hh2;
    f0 = *(const float2*)(fn + jb * HH + h);
    f1 = *(const float2*)(fn + (jb + 32) * HH + h);
    q0 = *(const float2*)(qn + h);
    q1 = *(const float2*)(qn + HH + h);
    m0 = *(const float2*)(mn + h);
    m1 = *(const float2*)(mn + HH + h);
  };

  float2 Rf0, Rf1, Rq0, Rq1, Rm0, Rm1;    // current hc operands
  float2 Sf0, Sf1, Sq0, Sq1, Sm0, Sm1;    // next hc operands
  pf(0, Rf0, Rf1, Rq0, Rq1, Rm0, Rm1);
  stageB(0, 0);  // chunk 0 -> buf 0
  stageB(1, 1);  // chunk 1 -> buf 1
  buildA(0, 0, Rf0, Rf1, Rq0, Rq1, Rm0, Rm1);
  // outstanding: chunk0(2) + chunk1(2); need chunk0 landed -> vmcnt(2)
  asm volatile("s_waitcnt vmcnt(2) lgkmcnt(0)\n\ts_barrier" ::: "memory");

#pragma unroll
  for (int c = 0; c < 32; ++c) {
    const int s = c & 3, hc = c >> 2;
    const int cb = c % 3, nb2 = (c + 1) % 3, fb = (c + 2) % 3;
    const bool pfphase = (s == 2) && (hc < 7);

    if (c + 2 < 32) stageB(fb, c + 2);
    if (pfphase) pf(hc + 1, Sf0, Sf1, Sq0, Sq1, Sm0, Sm1);
    if (c + 1 < 32) {
      if (((c + 1) & 3) == 0)
        buildA(nb2, 0, Sf0, Sf1, Sq0, Sq1, Sm0, Sm1);
      else
        buildA(nb2, (c + 1) & 3, Rf0, Rf1, Rq0, Rq1, Rm0, Rm1);
    }
    mfmaStep(cb);

    // counted-vmcnt barrier: chunk c+1's 2 stage loads landed; chunk c+2's
    // (and pf loads) stay in flight. c==30: nothing younger -> 0.
    if (c <= 29) {
      if (pfphase)
        asm volatile("s_waitcnt vmcnt(8) lgkmcnt(0)\n\ts_barrier" ::: "memory");
      else
        asm volatile("s_waitcnt vmcnt(2) lgkmcnt(0)\n\ts_barrier" ::: "memory");
    } else if (c == 30) {
      asm volatile("s_waitcnt vmcnt(0) lgkmcnt(0)\n\ts_barrier" ::: "memory");
    }
    if (s == 3) {
      Rf0 = Sf0; Rf1 = Sf1; Rq0 = Sq0; Rq1 = Sq1; Rm0 = Sm0; Rm1 = Sm1;
    }
  }

  // epilogue: tanh, scale by z2_w, reduce over k
  float psum[4][4];
#pragma unroll
  for (int mf = 0; mf < 4; ++mf)
#pragma unroll
    for (int v = 0; v < 4; ++v) psum[mf][v] = 0.f;

#pragma unroll
  for (int nf = 0; nf < 4; ++nf) {
    const int k = cg * 64 + nf * 16 + l15;
    const float zb = z1b[k], zw = z2w[k];
#pragma unroll
    for (int mf = 0; mf < 4; ++mf)
#pragma unroll
      for (int v = 0; v < 4; ++v) {
        const float x = acc[mf][nf][v] + zb;
        const float e = __expf(2.f * x);
        const float t = 1.f - 2.f / (e + 1.f);  // tanh(x)
        psum[mf][v] += zw * t;
      }
  }
#pragma unroll
  for (int d = 1; d < 16; d <<= 1)
#pragma unroll
    for (int mf = 0; mf < 4; ++mf)
#pragma unroll
      for (int v = 0; v < 4; ++v) psum[mf][v] += __shfl_xor(psum[mf][v], d, 64);
  if (l15 == 0) {
#pragma unroll
    for (int mf = 0; mf < 4; ++mf)
#pragma unroll
      for (int v = 0; v < 4; ++v)
        Gpart[rg * 64 + mf * 16 + q * 4 + v][cg] = psum[mf][v];
  }
  __syncthreads();
  if (tid < 128) {  // waves 0,1 fully active: wave = row i, lane = j
    const float gg = Gpart[tid][0] + Gpart[tid][1] + Gpart[tid][2] + Gpart[tid][3] + z2b[0];
    const int i = i0 + (tid >> 6), j = tid & 63;
    const int dl = doc_len[n];
    const float x = (j < dl && gg != 0.0f) ? gg : -INFINITY;  // where(G*mask==0,-inf)
    float mx = x;
#pragma unroll
    for (int d = 1; d < 64; d <<= 1) mx = fmaxf(mx, __shfl_xor(mx, d, 64));
    const float e = (x == -INFINITY) ? 0.f : __expf(x - mx);
    float s = e;
#pragma unroll
    for (int d = 1; d < 64; d <<= 1) s += __shfl_xor(s, d, 64);
    attn[(n * SS + i) * SS + j] = e / s;
  }
}

// ---------------------------------------------------------------------------
// Phase C: GRU-style scan, SPLIT into two dispatches (part 0: t 0..31,
// part 1: t 32..63) with BIT-EXACT handoff: the fp32 master state cm0/cm1
// (2 floats/lane) is saved to workspace; part 1 reconstructs the bf16 LDS C
// tile via the same cvtpk -> numerically identical to the unsplit kernel.
// (Purpose: each half ~38us drops below gate/prolog/nm in the rocprof top-5,
// exposing their steady-state durations; overhead ~3us.)
// cm0save aliases the z1wbf region (dead after gate_gemm); cm1save aliases
// the cbf region -- block X's cm1 slot [X*2048,+2048)B equals exactly block
// X's own final cbf rows, and part 1 reads its slot at kernel start before
// writing cbf at kernel end, so the overwrite is self-local and race-free.
// ---------------------------------------------------------------------------
__global__ __launch_bounds__(512, 2) void gru_scan(
    const unsigned short* __restrict__ wcat, const float* __restrict__ FWr,
    const float* __restrict__ FW, const float* __restrict__ Ub,
    const float* __restrict__ attn, unsigned short* __restrict__ Cout,
    float* __restrict__ cm0save, float* __restrict__ cm1save, const int part) {
  __shared__ unsigned short Cbf[2][4 * 272];  // stride 272 sh (136 dw, 8 mod 32 -> 2-way)
  __shared__ float attn_sT[64 * 4];           // [t][row]

  const int bi = blockIdx.x, n = bi >> 4, i0 = (bi & 15) * 4;
  const int tid = threadIdx.x, w = tid >> 6, l = tid & 63;
  const int l15 = l & 15, q = l >> 4;
  const int h0 = w * 32 + l15;  // lane's actual h cols: h0 and h0+16

  // persistent B-fragments: f=0/1 -> Ur cols h0/h0+16 ; f=2/3 -> U cols (K perm'd)
  short8 Bf[8][4];
#pragma unroll
  for (int f = 0; f < 4; ++f) {
    const int wrow = ((f >> 1) ? 256 : 0) + w * 32 + (f & 1) * 16 + l15;
    const unsigned short* bb = wcat + wrow * 256 + q * 8;
#pragma unroll
    for (int kt = 0; kt < 8; ++kt)
      Bf[kt][f] = *(const short8*)(bb + kt * 32);
  }

  const float ub0 = Ub[h0], ub1 = Ub[h0 + 16];

  for (int e = tid; e < 64 * 4; e += 512)  // attn transposed: [t][row]
    attn_sT[e] = attn[(n * SS + i0 + (e & 3)) * SS + (e >> 2)];

  float cm0, cm1;  // fp32 master state: (row q, h0) and (row q, h0+16)
  if (part == 0) {
    for (int e = tid; e < 544; e += 512)
      ((unsigned int*)Cbf[0])[e] = 0u;
    cm0 = 0.f; cm1 = 0.f;
  } else {
    // reconstruct bf16 C tile (state after t=31) from saved fp32 master state
    cm0 = cm0save[bi * 512 + tid];
    cm1 = cm1save[bi * 512 + tid];
    ((unsigned int*)Cbf[0])[q * 136 + w * 16 + l15] = cvtpk(cm0, cm1);
  }
  __syncthreads();

  const float* fwr_g = FWr + n * SS * HH;
  const float* fw_g  = FW + n * SS * HH;

  const int tbeg = part ? 32 : 0, tend = part ? 64 : 32;
  float fr0 = fwr_g[tbeg * HH + h0], fr1 = fwr_g[tbeg * HH + h0 + 16];
  float fc0 = fw_g[tbeg * HH + h0],  fc1 = fw_g[tbeg * HH + h0 + 16];

  for (int t = tbeg; t < tend; ++t) {
    const int cur = t & 1;
    const unsigned short* Cr = Cbf[cur];
    unsigned int* Cw = (unsigned int*)Cbf[cur ^ 1];

    // A-fragments: row (l15&3) -> 4-way broadcast read
    short8 Af[8];
    const int arow = (l15 & 3) * 272;
#pragma unroll
    for (int kt = 0; kt < 8; ++kt)
      Af[kt] = *(const short8*)&Cr[arow + kt * 32 + q * 8];

    // prefetch next step's FWr/FW (consumed next iteration -> latency hidden)
    float nr0 = 0.f, nr1 = 0.f, nc0 = 0.f, nc1 = 0.f;
    if (t < 63) {
      nr0 = fwr_g[(t + 1) * HH + h0];
      nr1 = fwr_g[(t + 1) * HH + h0 + 16];
      nc0 = fw_g[(t + 1) * HH + h0];
      nc1 = fw_g[(t + 1) * HH + h0 + 16];
    }

    const f32x4 z4 = {0.f, 0.f, 0.f, 0.f};
    f32x4 a0 = z4, a1 = z4, a2 = z4, a3 = z4;
    __builtin_amdgcn_s_setprio(1);
#pragma unroll
    for (int kt = 0; kt < 8; ++kt) {
      a0 = __builtin_amdgcn_mfma_f32_16x16x32_bf16(Af[kt], Bf[kt][0], a0, 0, 0, 0);
      a2 = __builtin_amdgcn_mfma_f32_16x16x32_bf16(Af[kt], Bf[kt][2], a2, 0, 0, 0);
    }
#pragma unroll
    for (int kt = 0; kt < 8; ++kt) {
      a1 = __builtin_amdgcn_mfma_f32_16x16x32_bf16(Af[kt], Bf[kt][1], a1, 0, 0, 0);
      a3 = __builtin_amdgcn_mfma_f32_16x16x32_bf16(Af[kt], Bf[kt][3], a3, 0, 0, 0);
    }
    __builtin_amdgcn_s_setprio(0);

    const float g = attn_sT[t * 4 + q];  // 16-lane broadcast

    // cell 0 (needs a0,a2 only -> VALU overlaps a1/a3 MFMA pipe drain)
    const float yr0 = sel4(a0, q), yu0 = sel4(a2, q);
    const float r0 = 1.f / (1.f + __expf(-(fr0 + yr0)));
    const float x0 = fc0 + r0 * (yu0 + ub0);
    const float e0 = __expf(2.f * x0);
    const float h0t = 1.f - 2.f / (e0 + 1.f);
    cm0 += g * (h0t - cm0);

    // cell 1
    const float yr1 = sel4(a1, q), yu1 = sel4(a3, q);
    const float r1 = 1.f / (1.f + __expf(-(fr1 + yr1)));
    const float x1 = fc1 + r1 * (yu1 + ub1);
    const float e1 = __expf(2.f * x1);
    const float h1t = 1.f - 2.f / (e1 + 1.f);
    cm1 += g * (h1t - cm1);

    Cw[q * 136 + w * 16 + l15] = cvtpk(cm0, cm1);  // storage cols (2*l15, 2*l15+1)

    fr0 = nr0; fr1 = nr1; fc0 = nc0; fc1 = nc1;
    __syncthreads();  // single barrier: C writes complete before next Af reads
  }

  if (part == 0) {
    cm0save[bi * 512 + tid] = cm0;
    cm1save[bi * 512 + tid] = cm1;
    return;
  }
  // final state in Cbf[0] (t=63 wrote buf 0); 4 rows x 128 dwords
  {
    const int row = tid >> 7, wo = tid & 127;
    ((unsigned int*)Cout)[(n * SS + i0 + row) * 128 + wo] =
        *(const unsigned int*)&Cbf[0][row * 272 + wo * 2];
  }
}

// ---------------------------------------------------------------------------
// Phase D: next_mem = relu([prevM | C | questions] @ nm_w^T + nm_b)
// BARRIER-FREE rewrite: A-fragments loaded per-lane DIRECT from global
// (pmbf/cbf/qbf are L2-resident; 16B/lane aligned) -- no LDS staging, no
// barriers (was 48/block). Tile 32x32, 256 blocks (all CUs), 128 threads.
// Same kt accumulation order -> bit-identical. nmbf's middle K-section
// carries the C K-permutation matching cbf.
// ---------------------------------------------------------------------------
__global__ __launch_bounds__(128) void next_mem_gemm(
    const unsigned short* __restrict__ pmbf, const unsigned short* __restrict__ cbf,
    const unsigned short* __restrict__ qbf, const unsigned short* __restrict__ nmbf,
    const float* __restrict__ nmb, float* __restrict__ out) {
  const int bi = blockIdx.x;
  const int rb = bi >> 3, cb = bi & 7;
  const int r0 = rb * 32, c0 = cb * 32;
  const int tid = threadIdx.x, w = tid >> 6, l = tid & 63;
  const int l15 = l & 15, q = l >> 4;

  const int arow = (r0 + w * 16 + l15) * HH + q * 8;  // A: per-lane row, 16B slice
  const unsigned short* nb = nmbf + (c0 + l15) * 768 + q * 8;

  const f32x4 z4 = {0.f, 0.f, 0.f, 0.f};
  f32x4 acc0 = z4, acc1 = z4;

#pragma unroll
  for (int kt = 0; kt < 8; ++kt) {  // K section 0: prevM
    const short8 Af = *(const short8*)(pmbf + arow + kt * 32);
    const short8 B0 = *(const short8*)(nb + kt * 32);
    const short8 B1 = *(const short8*)(nb + 16 * 768 + kt * 32);
    acc0 = __builtin_amdgcn_mfma_f32_16x16x32_bf16(Af, B0, acc0, 0, 0, 0);
    acc1 = __builtin_amdgcn_mfma_f32_16x16x32_bf16(Af, B1, acc1, 0, 0, 0);
  }
#pragma unroll
  for (int kt = 0; kt < 8; ++kt) {  // K section 1: C (K-permuted, matches nmbf mid)
    const short8 Af = *(const short8*)(cbf + arow + kt * 32);
    const short8 B0 = *(const short8*)(nb + 256 + kt * 32);
    const short8 B1 = *(const short8*)(nb + 16 * 768 + 256 + kt * 32);
    acc0 = __builtin_amdgcn_mfma_f32_16x16x32_bf16(Af, B0, acc0, 0, 0, 0);
    acc1 = __builtin_amdgcn_mfma_f32_16x16x32_bf16(Af, B1, acc1, 0, 0, 0);
  }
#pragma unroll
  for (int kt = 0; kt < 8; ++kt) {  // K section 2: questions
    const short8 Af = *(const short8*)(qbf + arow + kt * 32);
    const short8 B0 = *(const short8*)(nb + 512 + kt * 32);
    const short8 B1 = *(const short8*)(nb + 16 * 768 + 512 + kt * 32);
    acc0 = __builtin_amdgcn_mfma_f32_16x16x32_bf16(Af, B0, acc0, 0, 0, 0);
    acc1 = __builtin_amdgcn_mfma_f32_16x16x32_bf16(Af, B1, acc1, 0, 0, 0);
  }

#pragma unroll
  for (int nf = 0; nf < 2; ++nf) {
    const int col = c0 + nf * 16 + l15;
    const float bv = nmb[col];
    const f32x4 a = nf ? acc1 : acc0;
#pragma unroll
    for (int v = 0; v < 4; ++v) {
      const int grow = r0 + w * 16 + q * 4 + v;
      out[grow * HH + col] = fmaxf(a[v] + bv, 0.f);
    }
  }
}

// ---------------------------------------------------------------------------
extern "C" void kernel_launch(void* const* d_in, const int* in_sizes, int n_in,
                              void* d_out, int out_size, void* d_ws, size_t ws_size,
                              hipStream_t stream) {
  const float* facts     = (const float*)d_in[0];
  const float* prevM     = (const float*)d_in[1];
  const float* questions = (const float*)d_in[2];
  const int*   doc_len   = (const int*)d_in[3];
  const float* z1w = (const float*)d_in[4];
  const float* z1b = (const float*)d_in[5];
  const float* z2w = (const float*)d_in[6];
  const float* z2b = (const float*)d_in[7];
  const float* Wrw = (const float*)d_in[8];
  const float* Wrb = (const float*)d_in[9];
  const float* Urw = (const float*)d_in[10];
  const float* Urb = (const float*)d_in[11];
  const float* Ww  = (const float*)d_in[12];
  const float* Wb  = (const float*)d_in[13];
  const float* Uw  = (const float*)d_in[14];
  const float* Ub  = (const float*)d_in[15];
  const float* nmw = (const float*)d_in[16];
  const float* nmb = (const float*)d_in[17];

  char* ws = (char*)d_ws;
  unsigned short* z1wbf  = (unsigned short*)(ws + 0);        // 512 KB (dead after gate)
  unsigned short* wcatbf = (unsigned short*)(ws + 524288);   // 256 KB
  unsigned short* nmbf   = (unsigned short*)(ws + 786432);   // 384 KB
  unsigned short* pmbf   = (unsigned short*)(ws + 1179648);  // 512 KB
  unsigned short* qbf    = (unsigned short*)(ws + 1703936);  // 512 KB
  float* FWr = (float*)(ws + 2490368);                       // 1 MB
  float* FW  = (float*)(ws + 3538944);                       // 1 MB
  unsigned short* cbf = (unsigned short*)(ws + 4587520);     // 512 KB  (total ~4.9 MB)

  // gru split-state saves, aliasing DEAD regions (see gru_scan comment):
  float* cm0save = (float*)(ws + 0);        // z1wbf region, dead after gate_gemm
  float* cm1save = (float*)(ws + 4587520);  // cbf region, self-local overwrite

  float* out  = (float*)d_out;
  float* attn = out + NB * SS * HH;  // second output region

  prolog_fused<<<800, 256, 0, stream>>>(z1w, Urw, Uw, nmw, prevM, questions,
                                        z1wbf, wcatbf, nmbf, pmbf, qbf,
                                        facts, Wrw, Wrb, Urb, Ww, Wb, FWr, FW);
  gate_gemm<<<512, 512, 0, stream>>>(facts, prevM, questions, z1wbf, z1b, z2w, z2b,
                                     doc_len, attn);
  gru_scan<<<256, 512, 0, stream>>>(wcatbf, FWr, FW, Ub, attn, cbf, cm0save, cm1save, 0);
  gru_scan<<<256, 512, 0, stream>>>(wcatbf, FWr, FW, Ub, attn, cbf, cm0save, cm1save, 1);
  next_mem_gemm<<<256, 128, 0, stream>>>(pmbf, cbf, qbf, nmbf, nmb, out);
}

// Round 10
// 237.669 us; speedup vs baseline: 1.2094x; 1.0146x over previous
//
#include <hip/hip_runtime.h>
#include <hip/hip_bf16.h>
#include <math.h>

#define NB 16
#define SS 64
#define HH 256
#define FAA 256

using short8 = __attribute__((ext_vector_type(8))) short;
using f32x4  = __attribute__((ext_vector_type(4))) float;

__device__ __forceinline__ unsigned int cvtpk(float a, float b) {
  unsigned int r;
  asm("v_cvt_pk_bf16_f32 %0, %1, %2" : "=v"(r) : "v"(a), "v"(b));  // RNE, a->lo b->hi
  return r;
}
// select a[q] without runtime vector indexing (dyn-indexed regs -> scratch)
__device__ __forceinline__ float sel4(const f32x4 a, int q) {
  const float s01 = (q & 1) ? a[1] : a[0];
  const float s23 = (q & 1) ? a[3] : a[2];
  return (q & 2) ? s23 : s01;
}

// ---------------------------------------------------------------------------
// Fused prolog, VECTORIZED: 8 elems/thread (2x float4 loads + 4x cvt_pk +
// one 16B store). Block map: [0,128) z1w | [128,192) wcat | [192,288) nmbf |
// [288,416) pm | [416,544) q | [544,800) fact_proj.
// wcat/nmbf K-PERMUTATION (storage (g*32+2l, g*32+2l+1) = actual cols
// (g*32+l, g*32+16+l)) vectorizes as two contiguous float4 gathers.
// gru_scan stores C in the same permuted order -> phase D invariant.
// ---------------------------------------------------------------------------
__global__ __launch_bounds__(256) void prolog_fused(
    const float* __restrict__ z1w, const float* __restrict__ Ur,
    const float* __restrict__ U, const float* __restrict__ nmw,
    const float* __restrict__ pm, const float* __restrict__ qs,
    unsigned short* __restrict__ z1wbf, unsigned short* __restrict__ wcatbf,
    unsigned short* __restrict__ nmbf, unsigned short* __restrict__ pmbf,
    unsigned short* __restrict__ qbf,
    const float* __restrict__ facts, const float* __restrict__ Wr,
    const float* __restrict__ Wrb, const float* __restrict__ Urb,
    const float* __restrict__ Ww, const float* __restrict__ Wb,
    float* __restrict__ FWr, float* __restrict__ FW) {
  __shared__ float fl[4][HH];
  const int bid = blockIdx.x, tid = threadIdx.x;

  auto cvt8 = [&](const float* src, unsigned short* dst, int base) {
    const float4 a = *(const float4*)(src + base);
    const float4 b = *(const float4*)(src + base + 4);
    uint4 o;
    o.x = cvtpk(a.x, a.y); o.y = cvtpk(a.z, a.w);
    o.z = cvtpk(b.x, b.y); o.w = cvtpk(b.z, b.w);
    *(uint4*)(dst + base) = o;  // base mult of 8 -> 16B aligned
  };
  // permuted pair-pack: storage u32 w holds (row[c0+w], row[c0+16+w])
  auto cvt8perm = [&](const float* row, unsigned short* dst, int sbase, int c0) {
    const float4 lo = *(const float4*)(row + c0);
    const float4 hi = *(const float4*)(row + c0 + 16);
    uint4 o;
    o.x = cvtpk(lo.x, hi.x); o.y = cvtpk(lo.y, hi.y);
    o.z = cvtpk(lo.z, hi.z); o.w = cvtpk(lo.w, hi.w);
    *(uint4*)(dst + sbase) = o;
  };

  if (bid < 128) {               // z1w: 262144 elems
    const int base = (bid * 256 + tid) * 8;
    cvt8(z1w, z1wbf, base);
    return;
  }
  if (bid < 192) {               // wcat: 131072 elems, K-permuted
    const int base = ((bid - 128) * 256 + tid) * 8;
    const int o = base >> 8, s0 = base & 255;
    const int gb = s0 & ~31, t0 = s0 & 31;          // t0 in {0,8,16,24}
    const float* row = (o < 256) ? (Ur + o * 256) : (U + (o - 256) * 256);
    cvt8perm(row, wcatbf, base, gb + (t0 >> 1));
    return;
  }
  if (bid < 288) {               // nmbf: 196608 elems, middle section permuted
    const int base = ((bid - 192) * 256 + tid) * 8;
    const int o = base / 768, k0 = base - o * 768;
    const float* row = nmw + o * 768;
    if (k0 >= 256 && k0 < 512) {
      const int s0 = k0 - 256, gb = s0 & ~31, t0 = s0 & 31;
      cvt8perm(row, nmbf, base, 256 + gb + (t0 >> 1));
    } else {
      cvt8(row, nmbf + o * 768, k0);
    }
    return;
  }
  if (bid < 416) {               // prevM: 262144 elems
    const int base = ((bid - 288) * 256 + tid) * 8;
    cvt8(pm, pmbf, base);
    return;
  }
  if (bid < 544) {               // questions: 262144 elems
    const int base = ((bid - 416) * 256 + tid) * 8;
    cvt8(qs, qbf, base);
    return;
  }
  // ---- fact_proj: FWr[b,h] = facts[b]·Wr[h]+Wr_b[h]+Ur_b[h]; FW = facts[b]·W[h]+W_b[h]
  const int b0 = (bid - 544) * 4;
#pragma unroll
  for (int r = 0; r < 4; ++r) fl[r][tid] = facts[(b0 + r) * HH + tid];
  __syncthreads();
  float ar[4] = {0.f, 0.f, 0.f, 0.f}, aw[4] = {0.f, 0.f, 0.f, 0.f};
  const float4* wr = (const float4*)(Wr + tid * HH);
  const float4* ww = (const float4*)(Ww + tid * HH);
  for (int d4 = 0; d4 < 64; ++d4) {
    float4 a = wr[d4], b = ww[d4];
#pragma unroll
    for (int r = 0; r < 4; ++r) {
      float4 f = *(const float4*)&fl[r][d4 * 4];  // LDS broadcast
      ar[r] += a.x * f.x + a.y * f.y + a.z * f.z + a.w * f.w;
      aw[r] += b.x * f.x + b.y * f.y + b.z * f.z + b.w * f.w;
    }
  }
  const float br = Wrb[tid] + Urb[tid], bw = Wb[tid];
#pragma unroll
  for (int r = 0; r < 4; ++r) {
    FWr[(b0 + r) * HH + tid] = ar[r] + br;
    FW[(b0 + r) * HH + tid] = aw[r] + bw;
  }
}

// ---------------------------------------------------------------------------
// Phase A: gate GEMM + FUSED masked softmax. Block = (n, 2 i's) = 128 rows,
// 256 cols, K=1024 as 32 chunks of 32 (c = hc*4+s; accumulation order
// bit-identical to prior rounds).
// THIS ROUND (anti-spill): r9's WRITE_SIZE=22.7MB (output is 1MB) = scratch
// spills from the fully-unrolled 32-phase loop + S-prefetch regs under the
// launch_bounds(512,4) 128-reg cap (acc alone = 64 AGPR). Changes:
//  1. ROLLED main loop (was 32x unrolled: I-cache + allocator pressure)
//  2. S-prefetch register set DELETED (-24 VGPR): pf loads directly into R
//     at s==3, after mfmaStep consumed R, issued BEFORE stageB so every
//     barrier is a uniform vmcnt(2) (stage c+2 stays in flight; buildA's
//     auto-wait covers the pf loads).
// Phase order: mfma(cb) -> pf(s==3) -> stage(c+2) -> buildA(c+1) -> barrier.
// ---------------------------------------------------------------------------
__global__ __launch_bounds__(512, 4) void gate_gemm(
    const float* __restrict__ facts, const float* __restrict__ prevM,
    const float* __restrict__ questions, const unsigned short* __restrict__ z1wbf,
    const float* __restrict__ z1b, const float* __restrict__ z2w,
    const float* __restrict__ z2b, const int* __restrict__ doc_len,
    float* __restrict__ attn) {
  __shared__ unsigned short Ab[3][128 * 32];  // 8KB per buf
  __shared__ unsigned short Bb[3][256 * 32];  // 16KB per buf
  __shared__ float Gpart[128][4];

  const int bi = blockIdx.x;
  const int n = bi >> 5, i0 = (bi & 31) * 2;
  const int tid = threadIdx.x;
  const int w = tid >> 6, l = tid & 63;
  const int rg = w >> 2, cg = w & 3;        // rowgroup (2), colgroup (4)
  const int l15 = l & 15, q = l >> 4;
  const int t15 = tid & 15, jb = tid >> 4;  // builder mapping (jb 0..31)

  const float* fn = facts + n * SS * HH;
  const float* qn = questions + (n * SS + i0) * HH;
  const float* mn = prevM + (n * SS + i0) * HH;

  // stage B chunk c into Bb[buf]: wave w covers cols w*32..w*32+31; 2 loads/wave
  auto stageB = [&](int buf, int c) {
    const int kb = (c & 3) * 256 + (c >> 2) * 32;
    const int swz = ((l & 3) ^ ((l >> 2) & 3)) * 8;  // colg&3 == (l>>2)&3
#pragma unroll
    for (int j = 0; j < 2; ++j) {
      const int colg = w * 32 + j * 16 + (l >> 2);
      const unsigned short* src = z1wbf + colg * 1024 + kb + swz;
      __builtin_amdgcn_global_load_lds(src, Bb[buf] + (w * 32 + j * 16) * 32, 16, 0, 0);
    }
  };

  auto buildA = [&](int buf, int s, float2 f0, float2 f1, float2 q0, float2 q1,
                    float2 m0, float2 m1) {
    unsigned int* dst = (unsigned int*)Ab[buf];
    const int dsw = t15 ^ ((jb & 3) << 2);  // swizzled 4B-slot (row&3 == jb&3)
    const float2 o0 = (s & 1) ? m0 : q0;
    const float2 o1 = (s & 1) ? m1 : q1;
#pragma unroll
    for (int pl = 0; pl < 2; ++pl) {
      const float fx = pl ? f1.x : f0.x;
      const float fy = pl ? f1.y : f0.y;
#pragma unroll
      for (int il = 0; il < 2; ++il) {
        const int row = il * 64 + pl * 32 + jb;
        const float ox = il ? o1.x : o0.x;
        const float oy = il ? o1.y : o0.y;
        float a, b;
        if (s < 2) { a = fx * ox;         b = fy * oy; }
        else       { a = fabsf(fx - ox);  b = fabsf(fy - oy); }
        dst[row * 16 + dsw] = cvtpk(a, b);
      }
    }
  };

  const f32x4 zero4 = {0.f, 0.f, 0.f, 0.f};
  f32x4 acc[4][4];
#pragma unroll
  for (int a = 0; a < 4; ++a)
#pragma unroll
    for (int b = 0; b < 4; ++b) acc[a][b] = zero4;

  auto mfmaStep = [&](int buf) {
    short8 Bfr[4];
#pragma unroll
    for (int nf = 0; nf < 4; ++nf) {
      const int col = cg * 64 + nf * 16 + l15;
      Bfr[nf] = *(const short8*)&Bb[buf][col * 32 + (q ^ (l15 & 3)) * 8];
    }
    __builtin_amdgcn_s_setprio(1);
#pragma unroll
    for (int mf = 0; mf < 4; ++mf) {
      const int row = rg * 64 + mf * 16 + l15;
      const short8 Afm = *(const short8*)&Ab[buf][row * 32 + (q ^ (l15 & 3)) * 8];
#pragma unroll
      for (int nf = 0; nf < 4; ++nf)
        acc[mf][nf] = __builtin_amdgcn_mfma_f32_16x16x32_bf16(Afm, Bfr[nf], acc[mf][nf], 0, 0, 0);
    }
    __builtin_amdgcn_s_setprio(0);
  };

  const int hh2 = t15 * 2;
  float2 Rf0, Rf1, Rq0, Rq1, Rm0, Rm1;  // current-hc operands (single set)
  auto pf = [&](int hc) {
    const int h = hc * 32 + hh2;
    Rf0 = *(const float2*)(fn + jb * HH + h);
    Rf1 = *(const float2*)(fn + (jb + 32) * HH + h);
    Rq0 = *(const float2*)(qn + h);
    Rq1 = *(const float2*)(qn + HH + h);
    Rm0 = *(const float2*)(mn + h);
    Rm1 = *(const float2*)(mn + HH + h);
  };

  pf(0);
  stageB(0, 0);  // chunk 0 -> buf 0
  stageB(1, 1);  // chunk 1 -> buf 1
  buildA(0, 0, Rf0, Rf1, Rq0, Rq1, Rm0, Rm1);
  // outstanding: pf(12) + chunk0(2) + chunk1(2); need pf+chunk0 landed -> vmcnt(2)
  asm volatile("s_waitcnt vmcnt(2) lgkmcnt(0)\n\ts_barrier" ::: "memory");

  for (int c = 0; c < 32; ++c) {  // ROLLED: runtime buf indices, uniform branches
    const int s = c & 3, hc = c >> 2;
    const int cb = c % 3, nb2 = (c + 1) % 3, fb = (c + 2) % 3;

    mfmaStep(cb);  // consumes Ab[cb]/Bb[cb]; R operands dead for this hc after s==3

    if (s == 3 && hc < 7) pf(hc + 1);          // reload R for next hc (R dead)
    if (c + 2 < 32) stageB(fb, c + 2);         // youngest VMEM at barrier
    if (c + 1 < 32)
      buildA(nb2, (c + 1) & 3, Rf0, Rf1, Rq0, Rq1, Rm0, Rm1);

    // counted-vmcnt barrier: chunk c+1's 2 stage loads landed; chunk c+2's
    // stay in flight (pf loads already drained by buildA's auto-wait).
    if (c <= 29) {
      asm volatile("s_waitcnt vmcnt(2) lgkmcnt(0)\n\ts_barrier" ::: "memory");
    } else if (c == 30) {
      asm volatile("s_waitcnt vmcnt(0) lgkmcnt(0)\n\ts_barrier" ::: "memory");
    }
  }

  // epilogue: tanh, scale by z2_w, reduce over k
  float psum[4][4];
#pragma unroll
  for (int mf = 0; mf < 4; ++mf)
#pragma unroll
    for (int v = 0; v < 4; ++v) psum[mf][v] = 0.f;

#pragma unroll
  for (int nf = 0; nf < 4; ++nf) {
    const int k = cg * 64 + nf * 16 + l15;
    const float zb = z1b[k], zw = z2w[k];
#pragma unroll
    for (int mf = 0; mf < 4; ++mf)
#pragma unroll
      for (int v = 0; v < 4; ++v) {
        const float x = acc[mf][nf][v] + zb;
        const float e = __expf(2.f * x);
        const float t = 1.f - 2.f / (e + 1.f);  // tanh(x)
        psum[mf][v] += zw * t;
      }
  }
#pragma unroll
  for (int d = 1; d < 16; d <<= 1)
#pragma unroll
    for (int mf = 0; mf < 4; ++mf)
#pragma unroll
      for (int v = 0; v < 4; ++v) psum[mf][v] += __shfl_xor(psum[mf][v], d, 64);
  if (l15 == 0) {
#pragma unroll
    for (int mf = 0; mf < 4; ++mf)
#pragma unroll
      for (int v = 0; v < 4; ++v)
        Gpart[rg * 64 + mf * 16 + q * 4 + v][cg] = psum[mf][v];
  }
  __syncthreads();
  if (tid < 128) {  // waves 0,1 fully active: wave = row i, lane = j
    const float gg = Gpart[tid][0] + Gpart[tid][1] + Gpart[tid][2] + Gpart[tid][3] + z2b[0];
    const int i = i0 + (tid >> 6), j = tid & 63;
    const int dl = doc_len[n];
    const float x = (j < dl && gg != 0.0f) ? gg : -INFINITY;  // where(G*mask==0,-inf)
    float mx = x;
#pragma unroll
    for (int d = 1; d < 64; d <<= 1) mx = fmaxf(mx, __shfl_xor(mx, d, 64));
    const float e = (x == -INFINITY) ? 0.f : __expf(x - mx);
    float s = e;
#pragma unroll
    for (int d = 1; d < 64; d <<= 1) s += __shfl_xor(s, d, 64);
    attn[(n * SS + i) * SS + j] = e / s;
  }
}

// ---------------------------------------------------------------------------
// Phase C: GRU-style scan, SPLIT into two dispatches (part 0: t 0..31,
// part 1: t 32..63) with BIT-EXACT handoff via saved fp32 master state.
// (Diagnostic split kept: exposes steady-state durations of other kernels.)
// cm0save aliases z1wbf (dead after gate); cm1save aliases cbf (self-local
// overwrite, race-free -- see r8 analysis).
// ---------------------------------------------------------------------------
__global__ __launch_bounds__(512, 2) void gru_scan(
    const unsigned short* __restrict__ wcat, const float* __restrict__ FWr,
    const float* __restrict__ FW, const float* __restrict__ Ub,
    const float* __restrict__ attn, unsigned short* __restrict__ Cout,
    float* __restrict__ cm0save, float* __restrict__ cm1save, const int part) {
  __shared__ unsigned short Cbf[2][4 * 272];  // stride 272 sh (136 dw, 8 mod 32 -> 2-way)
  __shared__ float attn_sT[64 * 4];           // [t][row]

  const int bi = blockIdx.x, n = bi >> 4, i0 = (bi & 15) * 4;
  const int tid = threadIdx.x, w = tid >> 6, l = tid & 63;
  const int l15 = l & 15, q = l >> 4;
  const int h0 = w * 32 + l15;  // lane's actual h cols: h0 and h0+16

  // persistent B-fragments: f=0/1 -> Ur cols h0/h0+16 ; f=2/3 -> U cols (K perm'd)
  short8 Bf[8][4];
#pragma unroll
  for (int f = 0; f < 4; ++f) {
    const int wrow = ((f >> 1) ? 256 : 0) + w * 32 + (f & 1) * 16 + l15;
    const unsigned short* bb = wcat + wrow * 256 + q * 8;
#pragma unroll
    for (int kt = 0; kt < 8; ++kt)
      Bf[kt][f] = *(const short8*)(bb + kt * 32);
  }

  const float ub0 = Ub[h0], ub1 = Ub[h0 + 16];

  for (int e = tid; e < 64 * 4; e += 512)  // attn transposed: [t][row]
    attn_sT[e] = attn[(n * SS + i0 + (e & 3)) * SS + (e >> 2)];

  float cm0, cm1;  // fp32 master state: (row q, h0) and (row q, h0+16)
  if (part == 0) {
    for (int e = tid; e < 544; e += 512)
      ((unsigned int*)Cbf[0])[e] = 0u;
    cm0 = 0.f; cm1 = 0.f;
  } else {
    // reconstruct bf16 C tile (state after t=31) from saved fp32 master state
    cm0 = cm0save[bi * 512 + tid];
    cm1 = cm1save[bi * 512 + tid];
    ((unsigned int*)Cbf[0])[q * 136 + w * 16 + l15] = cvtpk(cm0, cm1);
  }
  __syncthreads();

  const float* fwr_g = FWr + n * SS * HH;
  const float* fw_g  = FW + n * SS * HH;

  const int tbeg = part ? 32 : 0, tend = part ? 64 : 32;
  float fr0 = fwr_g[tbeg * HH + h0], fr1 = fwr_g[tbeg * HH + h0 + 16];
  float fc0 = fw_g[tbeg * HH + h0],  fc1 = fw_g[tbeg * HH + h0 + 16];

  for (int t = tbeg; t < tend; ++t) {
    const int cur = t & 1;
    const unsigned short* Cr = Cbf[cur];
    unsigned int* Cw = (unsigned int*)Cbf[cur ^ 1];

    // A-fragments: row (l15&3) -> 4-way broadcast read
    short8 Af[8];
    const int arow = (l15 & 3) * 272;
#pragma unroll
    for (int kt = 0; kt < 8; ++kt)
      Af[kt] = *(const short8*)&Cr[arow + kt * 32 + q * 8];

    // prefetch next step's FWr/FW (consumed next iteration -> latency hidden)
    float nr0 = 0.f, nr1 = 0.f, nc0 = 0.f, nc1 = 0.f;
    if (t < 63) {
      nr0 = fwr_g[(t + 1) * HH + h0];
      nr1 = fwr_g[(t + 1) * HH + h0 + 16];
      nc0 = fw_g[(t + 1) * HH + h0];
      nc1 = fw_g[(t + 1) * HH + h0 + 16];
    }

    const f32x4 z4 = {0.f, 0.f, 0.f, 0.f};
    f32x4 a0 = z4, a1 = z4, a2 = z4, a3 = z4;
    __builtin_amdgcn_s_setprio(1);
#pragma unroll
    for (int kt = 0; kt < 8; ++kt) {
      a0 = __builtin_amdgcn_mfma_f32_16x16x32_bf16(Af[kt], Bf[kt][0], a0, 0, 0, 0);
      a2 = __builtin_amdgcn_mfma_f32_16x16x32_bf16(Af[kt], Bf[kt][2], a2, 0, 0, 0);
    }
#pragma unroll
    for (int kt = 0; kt < 8; ++kt) {
      a1 = __builtin_amdgcn_mfma_f32_16x16x32_bf16(Af[kt], Bf[kt][1], a1, 0, 0, 0);
      a3 = __builtin_amdgcn_mfma_f32_16x16x32_bf16(Af[kt], Bf[kt][3], a3, 0, 0, 0);
    }
    __builtin_amdgcn_s_setprio(0);

    const float g = attn_sT[t * 4 + q];  // 16-lane broadcast

    // cell 0 (needs a0,a2 only -> VALU overlaps a1/a3 MFMA pipe drain)
    const float yr0 = sel4(a0, q), yu0 = sel4(a2, q);
    const float r0 = 1.f / (1.f + __expf(-(fr0 + yr0)));
    const float x0 = fc0 + r0 * (yu0 + ub0);
    const float e0 = __expf(2.f * x0);
    const float h0t = 1.f - 2.f / (e0 + 1.f);
    cm0 += g * (h0t - cm0);

    // cell 1
    const float yr1 = sel4(a1, q), yu1 = sel4(a3, q);
    const float r1 = 1.f / (1.f + __expf(-(fr1 + yr1)));
    const float x1 = fc1 + r1 * (yu1 + ub1);
    const float e1 = __expf(2.f * x1);
    const float h1t = 1.f - 2.f / (e1 + 1.f);
    cm1 += g * (h1t - cm1);

    Cw[q * 136 + w * 16 + l15] = cvtpk(cm0, cm1);  // storage cols (2*l15, 2*l15+1)

    fr0 = nr0; fr1 = nr1; fc0 = nc0; fc1 = nc1;
    __syncthreads();  // single barrier: C writes complete before next Af reads
  }

  if (part == 0) {
    cm0save[bi * 512 + tid] = cm0;
    cm1save[bi * 512 + tid] = cm1;
    return;
  }
  // final state in Cbf[0] (t=63 wrote buf 0); 4 rows x 128 dwords
  {
    const int row = tid >> 7, wo = tid & 127;
    ((unsigned int*)Cout)[(n * SS + i0 + row) * 128 + wo] =
        *(const unsigned int*)&Cbf[0][row * 272 + wo * 2];
  }
}

// ---------------------------------------------------------------------------
// Phase D: next_mem = relu([prevM | C | questions] @ nm_w^T + nm_b)
// BARRIER-FREE: A-fragments per-lane direct from global (L2-resident).
// Tile 32x32, 256 blocks, 128 threads. Bit-identical accumulation order.
// ---------------------------------------------------------------------------
__global__ __launch_bounds__(128) void next_mem_gemm(
    const unsigned short* __restrict__ pmbf, const unsigned short* __restrict__ cbf,
    const unsigned short* __restrict__ qbf, const unsigned short* __restrict__ nmbf,
    const float* __restrict__ nmb, float* __restrict__ out) {
  const int bi = blockIdx.x;
  const int rb = bi >> 3, cb = bi & 7;
  const int r0 = rb * 32, c0 = cb * 32;
  const int tid = threadIdx.x, w = tid >> 6, l = tid & 63;
  const int l15 = l & 15, q = l >> 4;

  const int arow = (r0 + w * 16 + l15) * HH + q * 8;  // A: per-lane row, 16B slice
  const unsigned short* nb = nmbf + (c0 + l15) * 768 + q * 8;

  const f32x4 z4 = {0.f, 0.f, 0.f, 0.f};
  f32x4 acc0 = z4, acc1 = z4;

#pragma unroll
  for (int kt = 0; kt < 8; ++kt) {  // K section 0: prevM
    const short8 Af = *(const short8*)(pmbf + arow + kt * 32);
    const short8 B0 = *(const short8*)(nb + kt * 32);
    const short8 B1 = *(const short8*)(nb + 16 * 768 + kt * 32);
    acc0 = __builtin_amdgcn_mfma_f32_16x16x32_bf16(Af, B0, acc0, 0, 0, 0);
    acc1 = __builtin_amdgcn_mfma_f32_16x16x32_bf16(Af, B1, acc1, 0, 0, 0);
  }
#pragma unroll
  for (int kt = 0; kt < 8; ++kt) {  // K section 1: C (K-permuted, matches nmbf mid)
    const short8 Af = *(const short8*)(cbf + arow + kt * 32);
    const short8 B0 = *(const short8*)(nb + 256 + kt * 32);
    const short8 B1 = *(const short8*)(nb + 16 * 768 + 256 + kt * 32);
    acc0 = __builtin_amdgcn_mfma_f32_16x16x32_bf16(Af, B0, acc0, 0, 0, 0);
    acc1 = __builtin_amdgcn_mfma_f32_16x16x32_bf16(Af, B1, acc1, 0, 0, 0);
  }
#pragma unroll
  for (int kt = 0; kt < 8; ++kt) {  // K section 2: questions
    const short8 Af = *(const short8*)(qbf + arow + kt * 32);
    const short8 B0 = *(const short8*)(nb + 512 + kt * 32);
    const short8 B1 = *(const short8*)(nb + 16 * 768 + 512 + kt * 32);
    acc0 = __builtin_amdgcn_mfma_f32_16x16x32_bf16(Af, B0, acc0, 0, 0, 0);
    acc1 = __builtin_amdgcn_mfma_f32_16x16x32_bf16(Af, B1, acc1, 0, 0, 0);
  }

#pragma unroll
  for (int nf = 0; nf < 2; ++nf) {
    const int col = c0 + nf * 16 + l15;
    const float bv = nmb[col];
    const f32x4 a = nf ? acc1 : acc0;
#pragma unroll
    for (int v = 0; v < 4; ++v) {
      const int grow = r0 + w * 16 + q * 4 + v;
      out[grow * HH + col] = fmaxf(a[v] + bv, 0.f);
    }
  }
}

// ---------------------------------------------------------------------------
extern "C" void kernel_launch(void* const* d_in, const int* in_sizes, int n_in,
                              void* d_out, int out_size, void* d_ws, size_t ws_size,
                              hipStream_t stream) {
  const float* facts     = (const float*)d_in[0];
  const float* prevM     = (const float*)d_in[1];
  const float* questions = (const float*)d_in[2];
  const int*   doc_len   = (const int*)d_in[3];
  const float* z1w = (const float*)d_in[4];
  const float* z1b = (const float*)d_in[5];
  const float* z2w = (const float*)d_in[6];
  const float* z2b = (const float*)d_in[7];
  const float* Wrw = (const float*)d_in[8];
  const float* Wrb = (const float*)d_in[9];
  const float* Urw = (const float*)d_in[10];
  const float* Urb = (const float*)d_in[11];
  const float* Ww  = (const float*)d_in[12];
  const float* Wb  = (const float*)d_in[13];
  const float* Uw  = (const float*)d_in[14];
  const float* Ub  = (const float*)d_in[15];
  const float* nmw = (const float*)d_in[16];
  const float* nmb = (const float*)d_in[17];

  char* ws = (char*)d_ws;
  unsigned short* z1wbf  = (unsigned short*)(ws + 0);        // 512 KB (dead after gate)
  unsigned short* wcatbf = (unsigned short*)(ws + 524288);   // 256 KB
  unsigned short* nmbf   = (unsigned short*)(ws + 786432);   // 384 KB
  unsigned short* pmbf   = (unsigned short*)(ws + 1179648);  // 512 KB
  unsigned short* qbf    = (unsigned short*)(ws + 1703936);  // 512 KB
  float* FWr = (float*)(ws + 2490368);                       // 1 MB
  float* FW  = (float*)(ws + 3538944);                       // 1 MB
  unsigned short* cbf = (unsigned short*)(ws + 4587520);     // 512 KB  (total ~4.9 MB)

  // gru split-state saves, aliasing DEAD regions (see gru_scan comment):
  float* cm0save = (float*)(ws + 0);        // z1wbf region, dead after gate_gemm
  float* cm1save = (float*)(ws + 4587520);  // cbf region, self-local overwrite

  float* out  = (float*)d_out;
  float* attn = out + NB * SS * HH;  // second output region

  prolog_fused<<<800, 256, 0, stream>>>(z1w, Urw, Uw, nmw, prevM, questions,
                                        z1wbf, wcatbf, nmbf, pmbf, qbf,
                                        facts, Wrw, Wrb, Urb, Ww, Wb, FWr, FW);
  gate_gemm<<<512, 512, 0, stream>>>(facts, prevM, questions, z1wbf, z1b, z2w, z2b,
                                     doc_len, attn);
  gru_scan<<<256, 512, 0, stream>>>(wcatbf, FWr, FW, Ub, attn, cbf, cm0save, cm1save, 0);
  gru_scan<<<256, 512, 0, stream>>>(wcatbf, FWr, FW, Ub, attn, cbf, cm0save, cm1save, 1);
  next_mem_gemm<<<256, 128, 0, stream>>>(pmbf, cbf, qbf, nmbf, nmb, out);
}